// Round 10
// baseline (297.659 us; speedup 1.0000x reference)
//
#include <hip/hip_runtime.h>
#include <hip/hip_bf16.h>
#include <math.h>
#include <limits.h>

typedef __hip_bfloat16 bf16;
typedef __bf16 bf16x8 __attribute__((ext_vector_type(8)));
typedef float  f32x4  __attribute__((ext_vector_type(4)));

#define DEVI __device__ __forceinline__

static constexpr int Bb     = 2;
static constexpr int Ss     = 2048;
static constexpr int DMODEL = 1024;
static constexpr int NTOK   = Bb * Ss;   // 4096

DEVI float bf2f(bf16 v) { return __bfloat162float(v); }
DEVI bf16  f2bf(float v) { return __float2bfloat16(v); }

DEVI unsigned int packbf(float lo, float hi) {
  union { bf16 b; unsigned short u; } a, c;
  a.b = f2bf(lo); c.b = f2bf(hi);
  return ((unsigned int)c.u << 16) | a.u;
}

DEVI void async_load16(const bf16* g, bf16* l) {
  __builtin_amdgcn_global_load_lds((const __attribute__((address_space(1))) void*)g,
                                   (__attribute__((address_space(3))) void*)l, 16, 0, 0);
}

// ---------------------------------------------------------------- fp32 -> bf16 convert (x, Wdq, Wdkv)
__global__ __launch_bounds__(256) void convert3_kernel(
    const float* __restrict__ i0, bf16* __restrict__ o0, int n0,
    const float* __restrict__ i1, bf16* __restrict__ o1, int n1,
    const float* __restrict__ i2, bf16* __restrict__ o2, int n2) {
  int t = blockIdx.x * blockDim.x + threadIdx.x;
  const float* in; bf16* out;
  if (t < n0)           { in = i0; out = o0; }
  else if (t < n0 + n1) { t -= n0; in = i1; out = o1; }
  else if (t < n0 + n1 + n2) { t -= n0 + n1; in = i2; out = o2; }
  else return;
  const float4 v = ((const float4*)in)[t];
  uint2 o; o.x = packbf(v.x, v.y); o.y = packbf(v.z, v.w);
  *(uint2*)&out[(size_t)t * 4] = o;
}

// ---------------------------------------------------------------- fused weight transpose (+optional add)
struct TransDesc { const float* src; const float* src2; bf16* dst; int R; int C; int tstart; };
struct TransPack { TransDesc d[8]; };

__global__ __launch_bounds__(256) void transpose8_kernel(TransPack p) {
  const int t = blockIdx.x;
  int i = 0;
#pragma unroll
  for (int j = 1; j < 8; ++j) if (t >= p.d[j].tstart) i = j;
  const float* __restrict__ in  = p.d[i].src;
  const float* __restrict__ in2 = p.d[i].src2;
  bf16* __restrict__ out = p.d[i].dst;
  const int R = p.d[i].R, C = p.d[i].C;
  const int rel = t - p.d[i].tstart;
  const int tilesC = C >> 6;
  const int r0 = (rel / tilesC) * 64, c0 = (rel % tilesC) * 64;

  __shared__ bf16 tl[64][65];
  const int tc = threadIdx.x & 63, tr = threadIdx.x >> 6;
#pragma unroll
  for (int q = 0; q < 16; ++q) {
    int r = tr + q * 4;
    float v = in[(size_t)(r0 + r) * C + c0 + tc];
    if (in2) v += in2[(size_t)(r0 + r) * C + c0 + tc];
    tl[r][tc] = f2bf(v);
  }
  __syncthreads();
#pragma unroll
  for (int q = 0; q < 16; ++q) {
    int r = tr + q * 4;
    out[(size_t)(c0 + r) * R + r0 + tc] = tl[tc][r];
  }
}

// ---------------------------------------------------------------- prep: folded biases + p=0 fixup data
// qb[j] = Wdq_b@(Wuq+Wqr)[:,j] + Wuq_b[j] + Wqr_b[j]
// kb[j] = Wdkv_b@Wuk[:,j] + Wuk_b[j] + Wkr_b[j] ; vb[j] = Wdkv_b@Wuv[:,j] + Wuv_b[j]
// mqr01[i][t] = (Wdq@Wqr)[i][t] ; wkr01[i][t] = Wkr[i][t]
// fixb = { Wdq_b@Wqr[:,0]+Wqr_b[0], ..col1.., Wkr_b[0], Wkr_b[1] }
__global__ __launch_bounds__(256) void prep_kernel(
    const float* __restrict__ Wdq, const float* __restrict__ Wuq, const float* __restrict__ Wqr,
    const float* __restrict__ Wuk, const float* __restrict__ Wuv, const float* __restrict__ Wkr,
    const float* __restrict__ Wdq_b, const float* __restrict__ Wuq_b, const float* __restrict__ Wqr_b,
    const float* __restrict__ Wdkv_b, const float* __restrict__ Wuk_b, const float* __restrict__ Wkr_b,
    const float* __restrict__ Wuv_b,
    float* __restrict__ qb, float* __restrict__ kb, float* __restrict__ vb,
    float* __restrict__ mqr01, float* __restrict__ wkr01, float* __restrict__ fixb,
    float* __restrict__ zb) {
  const int t = blockIdx.x * blockDim.x + threadIdx.x;
  if (t < 1024) {
    const int j = t;
    float a = 0.f, bsum = 0.f, c = 0.f;
    for (int cc = 0; cc < 512; ++cc) {
      float w1 = Wdq_b[cc], w2 = Wdkv_b[cc];
      a    += w1 * (Wuq[(size_t)cc * 1024 + j] + Wqr[(size_t)cc * 1024 + j]);
      bsum += w2 * Wuk[(size_t)cc * 1024 + j];
      c    += w2 * Wuv[(size_t)cc * 1024 + j];
    }
    qb[j] = a + Wuq_b[j] + Wqr_b[j];
    kb[j] = bsum + Wuk_b[j] + Wkr_b[j];
    vb[j] = c + Wuv_b[j];
    zb[j] = 0.f;
  } else if (t < 3072) {
    const int idx = t - 1024, i = idx >> 1, tt = idx & 1;
    float s = 0.f;
    for (int cc = 0; cc < 512; ++cc) s += Wdq[(size_t)i * 512 + cc] * Wqr[(size_t)cc * 1024 + tt];
    mqr01[idx] = s;
    wkr01[idx] = Wkr[(size_t)i * 1024 + tt];
  } else if (t < 3076) {
    const int tt = t - 3072;
    if (tt < 2) {
      float s = 0.f;
      for (int cc = 0; cc < 512; ++cc) s += Wdq_b[cc] * Wqr[(size_t)cc * 1024 + tt];
      fixb[tt] = s + Wqr_b[tt];
    } else {
      fixb[tt] = Wkr_b[tt - 2];
    }
  }
}

// ---------------------------------------------------------------- batched GEMM (+optional addend matrix)
struct GemmDesc {
  const bf16* A; const bf16* WT; const float* b1; const float* b2; const bf16* addm; bf16* C;
  int lda, ldb, ldc, ldadd, K, bsplit, nTX, blkStart, biasRow;
};
struct GemmBatch { GemmDesc d[4]; };

__global__ __launch_bounds__(256) void gemm_batch_kernel(GemmBatch gb) {
  const int t = blockIdx.x;
  int di = 0;
#pragma unroll
  for (int j = 1; j < 4; ++j) if (t >= gb.d[j].blkStart) di = j;
  const GemmDesc D = gb.d[di];
  const int rel = t - D.blkStart;
  const int tileN = (rel % D.nTX) * 128;
  const int tileM = (rel / D.nTX) * 128;

  __shared__ bf16 ldsA[128 * 32];
  __shared__ bf16 ldsB[128 * 32];
  const int tid = threadIdx.x;
  const int lane = tid & 63;
  const int w = tid >> 6;
  const int wr = w >> 1, wc = w & 1;
  const int l15 = lane & 15, lg = lane >> 4;
  const int lrow = lane >> 2;
  const int lcol = (lane & 3) * 8;

  f32x4 acc[4][4] = {};

  for (int k0 = 0; k0 < D.K; k0 += 32) {
    async_load16(D.A  + (size_t)(tileM + w * 32 +      lrow) * D.lda + k0 + lcol, &ldsA[(w * 32) * 32]);
    async_load16(D.A  + (size_t)(tileM + w * 32 + 16 + lrow) * D.lda + k0 + lcol, &ldsA[(w * 32 + 16) * 32]);
    async_load16(D.WT + (size_t)(tileN + w * 32 +      lrow) * D.ldb + k0 + lcol, &ldsB[(w * 32) * 32]);
    async_load16(D.WT + (size_t)(tileN + w * 32 + 16 + lrow) * D.ldb + k0 + lcol, &ldsB[(w * 32 + 16) * 32]);
    __syncthreads();

    bf16x8 af[4], bfr[4];
#pragma unroll
    for (int i = 0; i < 4; ++i) {
      af[i]  = *(const bf16x8*)&ldsA[(wr * 64 + i * 16 + l15) * 32 + lg * 8];
      bfr[i] = *(const bf16x8*)&ldsB[(wc * 64 + i * 16 + l15) * 32 + lg * 8];
    }
#pragma unroll
    for (int i = 0; i < 4; ++i)
#pragma unroll
      for (int j = 0; j < 4; ++j)
        acc[i][j] = __builtin_amdgcn_mfma_f32_16x16x32_bf16(af[i], bfr[j], acc[i][j], 0, 0, 0);
    __syncthreads();
  }

  const int mbase = tileM + wr * 64;
  const int nbase = tileN + wc * 64;
#pragma unroll
  for (int j = 0; j < 4; ++j) {
    int col = nbase + j * 16 + l15;
    float bvc = D.biasRow ? 0.0f : (col < D.bsplit ? D.b1[col] : D.b2[col - D.bsplit]);
#pragma unroll
    for (int i = 0; i < 4; ++i)
#pragma unroll
      for (int r = 0; r < 4; ++r) {
        int row = mbase + i * 16 + lg * 4 + r;
        float bv = D.biasRow ? D.b1[row] : bvc;
        float v = acc[i][j][r] + bv;
        if (D.addm) v += bf2f(D.addm[(size_t)row * D.ldadd + col]);
        D.C[(size_t)row * D.ldc + col] = f2bf(v);
      }
  }
}

// ---------------------------------------------------------------- GEMM (fp32-out, for outproj)
__global__ __launch_bounds__(256) void gemm_kernel_f32(
    const bf16* __restrict__ A, int lda,
    const bf16* __restrict__ WT, int ldb,
    const float* __restrict__ b1,
    float* __restrict__ Cout, int ldc, int K) {
  __shared__ bf16 ldsA[128 * 32];
  __shared__ bf16 ldsB[128 * 32];
  const int tid = threadIdx.x;
  const int lane = tid & 63;
  const int w = tid >> 6;
  const int wr = w >> 1, wc = w & 1;
  const int tileM = blockIdx.y * 128;
  const int tileN = blockIdx.x * 128;
  const int l15 = lane & 15, lg = lane >> 4;
  const int lrow = lane >> 2;
  const int lcol = (lane & 3) * 8;

  f32x4 acc[4][4] = {};

  for (int k0 = 0; k0 < K; k0 += 32) {
    async_load16(A  + (size_t)(tileM + w * 32 +      lrow) * lda + k0 + lcol, &ldsA[(w * 32) * 32]);
    async_load16(A  + (size_t)(tileM + w * 32 + 16 + lrow) * lda + k0 + lcol, &ldsA[(w * 32 + 16) * 32]);
    async_load16(WT + (size_t)(tileN + w * 32 +      lrow) * ldb + k0 + lcol, &ldsB[(w * 32) * 32]);
    async_load16(WT + (size_t)(tileN + w * 32 + 16 + lrow) * ldb + k0 + lcol, &ldsB[(w * 32 + 16) * 32]);
    __syncthreads();

    bf16x8 af[4], bfr[4];
#pragma unroll
    for (int i = 0; i < 4; ++i) {
      af[i]  = *(const bf16x8*)&ldsA[(wr * 64 + i * 16 + l15) * 32 + lg * 8];
      bfr[i] = *(const bf16x8*)&ldsB[(wc * 64 + i * 16 + l15) * 32 + lg * 8];
    }
#pragma unroll
    for (int i = 0; i < 4; ++i)
#pragma unroll
      for (int j = 0; j < 4; ++j)
        acc[i][j] = __builtin_amdgcn_mfma_f32_16x16x32_bf16(af[i], bfr[j], acc[i][j], 0, 0, 0);
    __syncthreads();
  }

  const int mbase = tileM + wr * 64;
  const int nbase = tileN + wc * 64;
#pragma unroll
  for (int j = 0; j < 4; ++j) {
    int col = nbase + j * 16 + l15;
    float bvc = b1[col];
#pragma unroll
    for (int i = 0; i < 4; ++i)
#pragma unroll
      for (int r = 0; r < 4; ++r) {
        int row = mbase + i * 16 + lg * 4 + r;
        Cout[(size_t)row * ldc + col] = acc[i][j][r] + bvc;
      }
  }
}

// ---------------------------------------------------------------- p=0 pair fixup for Q,K (dims 0,1)
// wave per row: qr01 = x_row . mqr01 + fixb[0:2]; kr01 = x_row . wkr01 + fixb[2:4]
// Q[0] += qr0*(c-1) - qr1*s ; Q[1] += qr1*(c-1) + qr0*s  (same for K)
__global__ __launch_bounds__(256) void fixup_kernel(
    const bf16* __restrict__ x_bf, const float* __restrict__ mqr01,
    const float* __restrict__ wkr01, const float* __restrict__ fixb,
    bf16* __restrict__ Qn, bf16* __restrict__ Kn) {
  const int row = blockIdx.x * 4 + (threadIdx.x >> 6);
  const int lane = threadIdx.x & 63;
  float q0 = 0.f, q1 = 0.f, k0 = 0.f, k1 = 0.f;
  const bf16* xr = x_bf + (size_t)row * DMODEL + lane * 16;
  const float* mq = mqr01 + lane * 32;
  const float* mk = wkr01 + lane * 32;
#pragma unroll
  for (int e = 0; e < 16; ++e) {
    float xv = bf2f(xr[e]);
    q0 = fmaf(xv, mq[e * 2 + 0], q0);
    q1 = fmaf(xv, mq[e * 2 + 1], q1);
    k0 = fmaf(xv, mk[e * 2 + 0], k0);
    k1 = fmaf(xv, mk[e * 2 + 1], k1);
  }
#pragma unroll
  for (int d = 32; d >= 1; d >>= 1) {
    q0 += __shfl_xor(q0, d, 64);
    q1 += __shfl_xor(q1, d, 64);
    k0 += __shfl_xor(k0, d, 64);
    k1 += __shfl_xor(k1, d, 64);
  }
  if (lane == 0) {
    const float rr = (float)(row & (Ss - 1)) * (1.0f / 512.0f);
    const float c = cosf(rr) - 1.0f, sn = sinf(rr);
    const float qr0 = q0 + fixb[0], qr1 = q1 + fixb[1];
    const float kr0 = k0 + fixb[2], kr1 = k1 + fixb[3];
    const size_t base = (size_t)row * DMODEL;
    Qn[base]     = f2bf(bf2f(Qn[base])     + qr0 * c - qr1 * sn);
    Qn[base + 1] = f2bf(bf2f(Qn[base + 1]) + qr1 * c + qr0 * sn);
    Kn[base]     = f2bf(bf2f(Kn[base])     + kr0 * c - kr1 * sn);
    Kn[base + 1] = f2bf(bf2f(Kn[base + 1]) + kr1 * c + kr0 * sn);
  }
}

// ---------------------------------------------------------------- attention v5 (unchanged from round 9)
__global__ __launch_bounds__(256) void attn_kernel(
    const bf16* __restrict__ Qn, const bf16* __restrict__ Kn,
    const bf16* __restrict__ VT, bf16* __restrict__ AO) {
  const int bh = blockIdx.x, qt = blockIdx.y;   // bh%8 == XCD -> K/V stays in one L2
  const int b = bh >> 4, h = bh & 15;
  const int tid = threadIdx.x, lane = tid & 63, w = tid >> 6;
  const int q0 = qt * 64 + w * 16;
  const int l15 = lane & 15, lg = lane >> 4;
  const float SC2 = 0.044736075f;    // (1/sqrt(1040)) * log2(e)
  const float THR = 11.5415603f;     // 8 * log2(e)

  __shared__ bf16 ldsK[2][64 * 64];
  __shared__ bf16 ldsV[2][64 * 64];
  __shared__ bf16 ldsP[4][16 * 64];

  const bf16* Kg = Kn + (size_t)(b * Ss) * DMODEL + h * 64;
  const bf16* Vg = VT + (size_t)(h * 64) * NTOK + b * Ss;

  const int r0 = tid >> 3;
  const int srcb = ((tid & 7) * 16) ^ ((r0 & 7) << 4);
  const char* kS0 = (const char*)(Kg + (size_t)r0 * DMODEL) + srcb;
  const char* kS1 = (const char*)(Kg + (size_t)(32 + r0) * DMODEL) + srcb;
  const char* vS0 = (const char*)(Vg + (size_t)r0 * NTOK) + srcb;
  const char* vS1 = (const char*)(Vg + (size_t)(32 + r0) * NTOK) + srcb;
  const ptrdiff_t kAdv = (ptrdiff_t)64 * DMODEL * 2;
  const ptrdiff_t vAdv = 128;

  bf16* kd0_b0 = &ldsK[0][w * 512]; bf16* kd1_b0 = &ldsK[0][2048 + w * 512];
  bf16* kd0_b1 = &ldsK[1][w * 512]; bf16* kd1_b1 = &ldsK[1][2048 + w * 512];
  bf16* vd0_b0 = &ldsV[0][w * 512]; bf16* vd1_b0 = &ldsV[0][2048 + w * 512];
  bf16* vd0_b1 = &ldsV[1][w * 512]; bf16* vd1_b1 = &ldsV[1][2048 + w * 512];

  auto stageTo = [&](bf16* kd0, bf16* kd1, bf16* vd0, bf16* vd1) {
    async_load16((const bf16*)kS0, kd0);
    async_load16((const bf16*)kS1, kd1);
    async_load16((const bf16*)vS0, vd0);
    async_load16((const bf16*)vS1, vd1);
    kS0 += kAdv; kS1 += kAdv; vS0 += vAdv; vS1 += vAdv;
  };

  const int kswz = (l15 & 7) << 4;
  const int xA = (lg * 16) ^ kswz;
  const int xB = (64 + lg * 16) ^ kswz;
  const char* krA0 = (const char*)&ldsK[0][0] + l15 * 128 + xA;
  const char* krB0 = (const char*)&ldsK[0][0] + l15 * 128 + xB;
  const char* krA1 = (const char*)&ldsK[1][0] + l15 * 128 + xA;
  const char* krB1 = (const char*)&ldsK[1][0] + l15 * 128 + xB;
  const char* vrA0 = (const char*)&ldsV[0][0] + l15 * 128 + xA;
  const char* vrB0 = (const char*)&ldsV[0][0] + l15 * 128 + xB;
  const char* vrA1 = (const char*)&ldsV[1][0] + l15 * 128 + xA;
  const char* vrB1 = (const char*)&ldsV[1][0] + l15 * 128 + xB;

  char* Pw = (char*)&ldsP[w][0];
  char* pwr[4];
#pragma unroll
  for (int j = 0; j < 4; ++j) {
    const int chunk = (j * 2 + (lg >> 1)) ^ (l15 & 7);
    pwr[j] = Pw + l15 * 128 + chunk * 16 + (lg & 1) * 8;
  }
  const char* paA = Pw + l15 * 128 + xA;
  const char* paB = Pw + l15 * 128 + xB;

  const bf16* Qbase = Qn + (size_t)(b * Ss + q0 + l15) * DMODEL + h * 64;
  bf16x8 bq0 = *(const bf16x8*)&Qbase[lg * 8];
  bf16x8 bq1 = *(const bf16x8*)&Qbase[32 + lg * 8];

  float m = 0.0f, l = 0.0f;
  f32x4 accO[4] = {};

  auto body = [&](const char* krA, const char* krB, const char* vrA, const char* vrB) {
    f32x4 sa[4] = {};
#pragma unroll
    for (int j = 0; j < 4; ++j) {
      bf16x8 ak0 = *(const bf16x8*)(krA + j * 2048);
      bf16x8 ak1 = *(const bf16x8*)(krB + j * 2048);
      sa[j] = __builtin_amdgcn_mfma_f32_16x16x32_bf16(ak0, bq0, sa[j], 0, 0, 0);
      sa[j] = __builtin_amdgcn_mfma_f32_16x16x32_bf16(ak1, bq1, sa[j], 0, 0, 0);
    }
    float pmaxr = -3.0e38f;
#pragma unroll
    for (int j = 0; j < 4; ++j)
#pragma unroll
      for (int r = 0; r < 4; ++r) pmaxr = fmaxf(pmaxr, sa[j][r]);
    if (__any(fmaf(pmaxr, SC2, -m) > THR)) {
      float px = fmaxf(pmaxr, __shfl_xor(pmaxr, 16, 64));
      px = fmaxf(px, __shfl_xor(px, 32, 64));
      float mnew = fmaxf(m, px * SC2);
      float corr = __builtin_amdgcn_exp2f(m - mnew);
      m = mnew; l *= corr;
      float cr[4];
#pragma unroll
      for (int r = 0; r < 4; ++r) cr[r] = __shfl(corr, lg * 4 + r, 64);
#pragma unroll
      for (int dj = 0; dj < 4; ++dj)
#pragma unroll
        for (int r = 0; r < 4; ++r) accO[dj][r] *= cr[r];
    }
    float p[4][4];
    float ts0 = 0.f, ts1 = 0.f;
#pragma unroll
    for (int j = 0; j < 4; ++j) {
#pragma unroll
      for (int r = 0; r < 4; ++r)
        p[j][r] = __builtin_amdgcn_exp2f(fmaf(sa[j][r], SC2, -m));
      ts0 += p[j][0] + p[j][2];
      ts1 += p[j][1] + p[j][3];
    }
    float ts = ts0 + ts1;
    ts += __shfl_xor(ts, 16, 64);
    ts += __shfl_xor(ts, 32, 64);
    l += ts;
#pragma unroll
    for (int j = 0; j < 4; ++j) {
      uint2 pw;
      pw.x = packbf(p[j][0], p[j][1]);
      pw.y = packbf(p[j][2], p[j][3]);
      *(uint2*)pwr[j] = pw;
    }
    bf16x8 pa0 = *(const bf16x8*)paA;
    bf16x8 pa1 = *(const bf16x8*)paB;
#pragma unroll
    for (int dj = 0; dj < 4; ++dj) {
      bf16x8 bv0 = *(const bf16x8*)(vrA + dj * 2048);
      bf16x8 bv1 = *(const bf16x8*)(vrB + dj * 2048);
      accO[dj] = __builtin_amdgcn_mfma_f32_16x16x32_bf16(pa0, bv0, accO[dj], 0, 0, 0);
      accO[dj] = __builtin_amdgcn_mfma_f32_16x16x32_bf16(pa1, bv1, accO[dj], 0, 0, 0);
    }
  };

  stageTo(kd0_b0, kd1_b0, vd0_b0, vd1_b0);
  for (int tt = 0; tt < 16; ++tt) {
    __syncthreads();
    stageTo(kd0_b1, kd1_b1, vd0_b1, vd1_b1);
    body(krA0, krB0, vrA0, vrB0);
    __syncthreads();
    if (tt < 15) stageTo(kd0_b0, kd1_b0, vd0_b0, vd1_b0);
    body(krA1, krB1, vrA1, vrB1);
  }

  float linv[4];
#pragma unroll
  for (int r = 0; r < 4; ++r) linv[r] = 1.0f / __shfl(l, lg * 4 + r, 64);
#pragma unroll
  for (int dj = 0; dj < 4; ++dj)
#pragma unroll
    for (int r = 0; r < 4; ++r)
      AO[(size_t)(b * Ss + q0 + lg * 4 + r) * DMODEL + h * 64 + dj * 16 + l15] =
          f2bf(accO[dj][r] * linv[r]);
}

// ---------------------------------------------------------------- launch
extern "C" void kernel_launch(void* const* d_in, const int* in_sizes, int n_in,
                              void* d_out, int out_size, void* d_ws, size_t ws_size,
                              hipStream_t stream) {
  const float* x      = (const float*)d_in[0];
  const float* Wdq    = (const float*)d_in[1];  const float* Wdq_b  = (const float*)d_in[2];
  const float* Wuq    = (const float*)d_in[3];  const float* Wuq_b  = (const float*)d_in[4];
  const float* Wqr    = (const float*)d_in[5];  const float* Wqr_b  = (const float*)d_in[6];
  const float* Wkr    = (const float*)d_in[7];  const float* Wkr_b  = (const float*)d_in[8];
  const float* Wdkv   = (const float*)d_in[9];  const float* Wdkv_b = (const float*)d_in[10];
  const float* Wuk    = (const float*)d_in[11]; const float* Wuk_b  = (const float*)d_in[12];
  const float* Wuv    = (const float*)d_in[13]; const float* Wuv_b  = (const float*)d_in[14];
  const float* Wo     = (const float*)d_in[15]; const float* Wo_b   = (const float*)d_in[16];

  // ---- workspace (~40 MB) ----
  char* ws = (char*)d_ws;
  size_t off = 0;
  bf16* WuqqrT = (bf16*)(ws + off); off += (size_t)1024 * 512  * 2;   // (Wuq+Wqr)^T
  bf16* WukT   = (bf16*)(ws + off); off += (size_t)1024 * 512  * 2;
  bf16* WuvT   = (bf16*)(ws + off); off += (size_t)1024 * 512  * 2;
  bf16* WkrT   = (bf16*)(ws + off); off += (size_t)1024 * 1024 * 2;
  bf16* WoT    = (bf16*)(ws + off); off += (size_t)1024 * 1024 * 2;
  bf16* Wdq_bf = (bf16*)(ws + off); off += (size_t)1024 * 512  * 2;
  bf16* Wdkv_bf= (bf16*)(ws + off); off += (size_t)1024 * 512  * 2;
  bf16* x_bf   = (bf16*)(ws + off); off += (size_t)NTOK * 1024 * 2;
  bf16* MqT    = (bf16*)(ws + off); off += (size_t)1024 * 1024 * 2;
  bf16* MkT    = (bf16*)(ws + off); off += (size_t)1024 * 1024 * 2;
  bf16* MvT    = (bf16*)(ws + off); off += (size_t)1024 * 1024 * 2;
  bf16* VTr    = (bf16*)(ws + off); off += (size_t)NTOK * 1024 * 2;
  bf16* AO     = (bf16*)(ws + off); off += (size_t)NTOK * 1024 * 2;
  float* qb    = (float*)(ws + off); off += 1024 * 4;
  float* kb    = (float*)(ws + off); off += 1024 * 4;
  float* vb    = (float*)(ws + off); off += 1024 * 4;
  float* zb    = (float*)(ws + off); off += 1024 * 4;
  float* mqr01 = (float*)(ws + off); off += 2048 * 4;
  float* wkr01 = (float*)(ws + off); off += 2048 * 4;
  float* fixb  = (float*)(ws + off); off += 4 * 4;
  bf16* Qn     = (bf16*)d_out;                         // dead before final GEMM
  bf16* Kn     = (bf16*)d_out + (size_t)NTOK * DMODEL;
  (void)ws_size; (void)in_sizes; (void)n_in; (void)out_size;

  // converts: x, Wdq, Wdkv -> bf16
  const int nx = NTOK * DMODEL / 4, nw = 1024 * 512 / 4;
  convert3_kernel<<<(nx + 2 * nw + 255) / 256, 256, 0, stream>>>(
      x, x_bf, nx, Wdq, Wdq_bf, nw, Wdkv, Wdkv_bf, nw);

  // weight transposes (+Wuq+Wqr add)
  TransPack tp = {{
    { Wuq, Wqr,  WuqqrT, 512,  1024, 0        },
    { Wuk, 0,    WukT,   512,  1024, 128      },
    { Wuv, 0,    WuvT,   512,  1024, 256      },
    { Wkr, 0,    WkrT,   1024, 1024, 384      },
    { Wo,  0,    WoT,    1024, 1024, 640      },
    { 0, 0, 0, 0, 0, 1 << 30 }, { 0, 0, 0, 0, 0, 1 << 30 }, { 0, 0, 0, 0, 0, 1 << 30 },
  }};
  transpose8_kernel<<<896, 256, 0, stream>>>(tp);

  // folded biases + fixup data
  prep_kernel<<<13, 256, 0, stream>>>(Wdq, Wuq, Wqr, Wuk, Wuv, Wkr,
                                      Wdq_b, Wuq_b, Wqr_b, Wdkv_b, Wuk_b, Wkr_b, Wuv_b,
                                      qb, kb, vb, mqr01, wkr01, fixb, zb);

  // ---- fold batch (192 blocks): MqT = WuqqrT@Wdq^T ; MkT = WukT@Wdkv^T + WkrT ; MvT = WuvT@Wdkv^T
  GemmBatch fb = {{
    { WuqqrT, Wdq_bf,  zb, zb, 0,    MqT, 512, 512, 1024, 0,    512, INT_MAX, 8, 0,       0 },
    { WukT,   Wdkv_bf, zb, zb, WkrT, MkT, 512, 512, 1024, 1024, 512, INT_MAX, 8, 64,      0 },
    { WuvT,   Wdkv_bf, zb, zb, 0,    MvT, 512, 512, 1024, 0,    512, INT_MAX, 8, 128,     0 },
    { 0, 0, 0, 0, 0, 0, 0, 0, 0, 0, 0, 0, 1, 1 << 30, 0 },
  }};
  gemm_batch_kernel<<<192, 256, 0, stream>>>(fb);

  // ---- main batch (768 blocks): Qn = x@MqT^T + qb ; Kn = x@MkT^T + kb ; VTr = MvT@x^T + vb(row)
  GemmBatch mb = {{
    { x_bf, MqT,  qb, qb, 0, Qn,  1024, 1024, 1024, 0, 1024, INT_MAX, 8,  0,       0 },
    { x_bf, MkT,  kb, kb, 0, Kn,  1024, 1024, 1024, 0, 1024, INT_MAX, 8,  256,     0 },
    { MvT,  x_bf, vb, vb, 0, VTr, 1024, 1024, NTOK, 0, 1024, INT_MAX, 32, 512,     1 },
    { 0, 0, 0, 0, 0, 0, 0, 0, 0, 0, 0, 0, 1, 1 << 30, 0 },
  }};
  gemm_batch_kernel<<<768, 256, 0, stream>>>(mb);

  // p=0 rope fixup on Q,K dims 0,1
  fixup_kernel<<<NTOK / 4, 256, 0, stream>>>(x_bf, mqr01, wkr01, fixb, Qn, Kn);

  // attention (bh on x for XCD-L2 pinning)
  attn_kernel<<<dim3(32, 32), 256, 0, stream>>>(Qn, Kn, VTr, AO);

  // output projection (fp32 out)
  gemm_kernel_f32<<<dim3(8, 32), 256, 0, stream>>>(
      AO, 1024, WoT, 1024, Wo_b, (float*)d_out, 1024, 1024);
}

// Round 11
// 189.585 us; speedup vs baseline: 1.5701x; 1.5701x over previous
//
#include <hip/hip_runtime.h>
#include <hip/hip_bf16.h>
#include <math.h>
#include <limits.h>

typedef __hip_bfloat16 bf16;
typedef __bf16 bf16x8 __attribute__((ext_vector_type(8)));
typedef float  f32x4  __attribute__((ext_vector_type(4)));

#define DEVI __device__ __forceinline__

static constexpr int Bb     = 2;
static constexpr int Ss     = 2048;
static constexpr int DMODEL = 1024;
static constexpr int NTOK   = Bb * Ss;   // 4096

DEVI float bf2f(bf16 v) { return __bfloat162float(v); }
DEVI bf16  f2bf(float v) { return __float2bfloat16(v); }

DEVI unsigned int packbf(float lo, float hi) {
  union { bf16 b; unsigned short u; } a, c;
  a.b = f2bf(lo); c.b = f2bf(hi);
  return ((unsigned int)c.u << 16) | a.u;
}
DEVI float bfu2f(unsigned short u) {
  unsigned int x = (unsigned int)u << 16;
  float f; __builtin_memcpy(&f, &x, 4); return f;
}

DEVI void async_load16(const bf16* g, bf16* l) {
  __builtin_amdgcn_global_load_lds((const __attribute__((address_space(1))) void*)g,
                                   (__attribute__((address_space(3))) void*)l, 16, 0, 0);
}

// ---------------------------------------------------------------- transpose (1280 tiles) + convert (4096 blocks), one dispatch
struct TransDesc { const float* src; bf16* dst; int R; int C; int tstart; };
struct TransPack { TransDesc d[8]; };

__global__ __launch_bounds__(256) void trans_conv_kernel(
    TransPack p, const float* __restrict__ cx, bf16* __restrict__ cxo, int tstartConv) {
  __shared__ bf16 tl[64][65];
  const int t = blockIdx.x;
  if (t >= tstartConv) {
    // ---- convert range: one float4 per thread
    const int idx = (t - tstartConv) * 256 + threadIdx.x;
    const float4 v = ((const float4*)cx)[idx];
    uint2 o; o.x = packbf(v.x, v.y); o.y = packbf(v.z, v.w);
    *(uint2*)&cxo[(size_t)idx * 4] = o;
    return;
  }
  // ---- transpose range
  int i = 0;
#pragma unroll
  for (int j = 1; j < 8; ++j) if (t >= p.d[j].tstart) i = j;
  const float* __restrict__ in = p.d[i].src;
  bf16* __restrict__ out = p.d[i].dst;
  const int R = p.d[i].R, C = p.d[i].C;
  const int rel = t - p.d[i].tstart;
  const int tilesC = C >> 6;
  const int r0 = (rel / tilesC) * 64, c0 = (rel % tilesC) * 64;
  const int tc = threadIdx.x & 63, tr = threadIdx.x >> 6;
#pragma unroll
  for (int q = 0; q < 16; ++q) {
    int r = tr + q * 4;
    tl[r][tc] = f2bf(in[(size_t)(r0 + r) * C + c0 + tc]);
  }
  __syncthreads();
#pragma unroll
  for (int q = 0; q < 16; ++q) {
    int r = tr + q * 4;
    out[(size_t)(c0 + r) * R + r0 + tc] = tl[tc][r];
  }
}

// ---------------------------------------------------------------- batched GEMM
struct GemmDesc {
  const bf16* A; const bf16* WT; const float* b1; const float* b2; bf16* C;
  int lda, ldb, ldc, K, bsplit, nTX, blkStart, biasRow;
};
struct GemmBatch { GemmDesc d[4]; };

__global__ __launch_bounds__(256) void gemm_batch_kernel(GemmBatch gb) {
  const int t = blockIdx.x;
  int di = 0;
#pragma unroll
  for (int j = 1; j < 4; ++j) if (t >= gb.d[j].blkStart) di = j;
  const GemmDesc D = gb.d[di];
  const int rel = t - D.blkStart;
  const int tileN = (rel % D.nTX) * 128;
  const int tileM = (rel / D.nTX) * 128;

  __shared__ bf16 ldsA[128 * 32];
  __shared__ bf16 ldsB[128 * 32];
  const int tid = threadIdx.x;
  const int lane = tid & 63;
  const int w = tid >> 6;
  const int wr = w >> 1, wc = w & 1;
  const int l15 = lane & 15, lg = lane >> 4;
  const int lrow = lane >> 2;
  const int lcol = (lane & 3) * 8;

  f32x4 acc[4][4] = {};

  for (int k0 = 0; k0 < D.K; k0 += 32) {
    async_load16(D.A  + (size_t)(tileM + w * 32 +      lrow) * D.lda + k0 + lcol, &ldsA[(w * 32) * 32]);
    async_load16(D.A  + (size_t)(tileM + w * 32 + 16 + lrow) * D.lda + k0 + lcol, &ldsA[(w * 32 + 16) * 32]);
    async_load16(D.WT + (size_t)(tileN + w * 32 +      lrow) * D.ldb + k0 + lcol, &ldsB[(w * 32) * 32]);
    async_load16(D.WT + (size_t)(tileN + w * 32 + 16 + lrow) * D.ldb + k0 + lcol, &ldsB[(w * 32 + 16) * 32]);
    __syncthreads();

    bf16x8 af[4], bfr[4];
#pragma unroll
    for (int i = 0; i < 4; ++i) {
      af[i]  = *(const bf16x8*)&ldsA[(wr * 64 + i * 16 + l15) * 32 + lg * 8];
      bfr[i] = *(const bf16x8*)&ldsB[(wc * 64 + i * 16 + l15) * 32 + lg * 8];
    }
#pragma unroll
    for (int i = 0; i < 4; ++i)
#pragma unroll
      for (int j = 0; j < 4; ++j)
        acc[i][j] = __builtin_amdgcn_mfma_f32_16x16x32_bf16(af[i], bfr[j], acc[i][j], 0, 0, 0);
    __syncthreads();
  }

  const int mbase = tileM + wr * 64;
  const int nbase = tileN + wc * 64;
#pragma unroll
  for (int j = 0; j < 4; ++j) {
    int col = nbase + j * 16 + l15;
    float bvc = D.biasRow ? 0.0f : (col < D.bsplit ? D.b1[col] : D.b2[col - D.bsplit]);
#pragma unroll
    for (int i = 0; i < 4; ++i)
#pragma unroll
      for (int r = 0; r < 4; ++r) {
        int row = mbase + i * 16 + lg * 4 + r;
        float bv = D.biasRow ? D.b1[row] : bvc;
        D.C[(size_t)row * D.ldc + col] = f2bf(acc[i][j][r] + bv);
      }
  }
}

// ---------------------------------------------------------------- GEMM fp32-out (outproj), 128x64 tiles
__global__ __launch_bounds__(256) void gemm_kernel_f32(
    const bf16* __restrict__ A, int lda,
    const bf16* __restrict__ WT, int ldb,
    const float* __restrict__ b1,
    float* __restrict__ Cout, int ldc, int K) {
  __shared__ bf16 ldsA[128 * 32];
  __shared__ bf16 ldsB[64 * 32];
  const int tid = threadIdx.x;
  const int lane = tid & 63;
  const int w = tid >> 6;                 // wave owns rows [w*32, w*32+32)
  const int tileM = blockIdx.y * 128;
  const int tileN = blockIdx.x * 64;
  const int l15 = lane & 15, lg = lane >> 4;
  const int lrow = lane >> 2;
  const int lcol = (lane & 3) * 8;

  f32x4 acc[2][4] = {};

  for (int k0 = 0; k0 < K; k0 += 32) {
    async_load16(A  + (size_t)(tileM + w * 32 +      lrow) * lda + k0 + lcol, &ldsA[(w * 32) * 32]);
    async_load16(A  + (size_t)(tileM + w * 32 + 16 + lrow) * lda + k0 + lcol, &ldsA[(w * 32 + 16) * 32]);
    async_load16(WT + (size_t)(tileN + w * 16 + lrow) * ldb + k0 + lcol, &ldsB[(w * 16) * 32]);
    __syncthreads();

    bf16x8 af[2], bfr[4];
#pragma unroll
    for (int i = 0; i < 2; ++i)
      af[i]  = *(const bf16x8*)&ldsA[(w * 32 + i * 16 + l15) * 32 + lg * 8];
#pragma unroll
    for (int j = 0; j < 4; ++j)
      bfr[j] = *(const bf16x8*)&ldsB[(j * 16 + l15) * 32 + lg * 8];
#pragma unroll
    for (int i = 0; i < 2; ++i)
#pragma unroll
      for (int j = 0; j < 4; ++j)
        acc[i][j] = __builtin_amdgcn_mfma_f32_16x16x32_bf16(af[i], bfr[j], acc[i][j], 0, 0, 0);
    __syncthreads();
  }

#pragma unroll
  for (int j = 0; j < 4; ++j) {
    int col = tileN + j * 16 + l15;
    float bvc = b1[col];
#pragma unroll
    for (int i = 0; i < 2; ++i)
#pragma unroll
      for (int r = 0; r < 4; ++r) {
        int row = tileM + w * 32 + i * 16 + lg * 4 + r;
        Cout[(size_t)row * ldc + col] = acc[i][j][r] + bvc;
      }
  }
}

// ---------------------------------------------------------------- combine + rope
__global__ __launch_bounds__(256) void combine_rope_kernel(
    const bf16* __restrict__ Gc, int ldc_,
    const bf16* __restrict__ Gr, int ldr_,
    bf16* __restrict__ out) {
  const int t = blockIdx.x * blockDim.x + threadIdx.x;   // NTOK*128
  const int g = t & 127, row = t >> 7;
  const int s = row & (Ss - 1);
  union { bf16x8 v; unsigned short u[8]; } vc, vr;
  vc.v = *(const bf16x8*)&Gc[(size_t)row * ldc_ + (size_t)g * 8];
  vr.v = *(const bf16x8*)&Gr[(size_t)row * ldr_ + (size_t)g * 8];
  uint4 o;
  unsigned int* op = &o.x;
#pragma unroll
  for (int qq = 0; qq < 4; ++qq) {
    const int p = g * 4 + qq;
    float c, sn;
    if (p == 0) {
      float rr = (float)s * (1.0f / 512.0f);
      c = cosf(rr); sn = sinf(rr);
    } else {
      // theta = 10000^(-2p)/512; for p>=1, r <= 4e-8 -> cosf(r)==1.0f, sinf(r)==r (fp32-exact)
      float theta = exp2f(-26.5754247590989f * (float)p) * (1.0f / 512.0f);
      sn = (float)s * theta; c = 1.0f;
    }
    float g0 = bfu2f(vr.u[2 * qq]), g1 = bfu2f(vr.u[2 * qq + 1]);
    float c0 = bfu2f(vc.u[2 * qq]), c1 = bfu2f(vc.u[2 * qq + 1]);
    op[qq] = packbf(c0 + g0 * c - g1 * sn, c1 + g1 * c + g0 * sn);
  }
  *(uint4*)&out[(size_t)row * DMODEL + (size_t)g * 8] = o;
}

// ---------------------------------------------------------------- attention v5.1 (round 9 + setprio)
__global__ __launch_bounds__(256) void attn_kernel(
    const bf16* __restrict__ Qn, const bf16* __restrict__ Kn,
    const bf16* __restrict__ VT, bf16* __restrict__ AO) {
  const int bh = blockIdx.x, qt = blockIdx.y;   // bh%8 == XCD -> K/V stays in one L2
  const int b = bh >> 4, h = bh & 15;
  const int tid = threadIdx.x, lane = tid & 63, w = tid >> 6;
  const int q0 = qt * 64 + w * 16;
  const int l15 = lane & 15, lg = lane >> 4;
  const float SC2 = 0.044736075f;    // (1/sqrt(1040)) * log2(e)
  const float THR = 11.5415603f;     // 8 * log2(e)

  __shared__ bf16 ldsK[2][64 * 64];
  __shared__ bf16 ldsV[2][64 * 64];
  __shared__ bf16 ldsP[4][16 * 64];

  const bf16* Kg = Kn + (size_t)(b * Ss) * DMODEL + h * 64;
  const bf16* Vg = VT + (size_t)(h * 64) * NTOK + b * Ss;

  const int r0 = tid >> 3;
  const int srcb = ((tid & 7) * 16) ^ ((r0 & 7) << 4);
  const char* kS0 = (const char*)(Kg + (size_t)r0 * DMODEL) + srcb;
  const char* kS1 = (const char*)(Kg + (size_t)(32 + r0) * DMODEL) + srcb;
  const char* vS0 = (const char*)(Vg + (size_t)r0 * NTOK) + srcb;
  const char* vS1 = (const char*)(Vg + (size_t)(32 + r0) * NTOK) + srcb;
  const ptrdiff_t kAdv = (ptrdiff_t)64 * DMODEL * 2;
  const ptrdiff_t vAdv = 128;

  bf16* kd0_b0 = &ldsK[0][w * 512]; bf16* kd1_b0 = &ldsK[0][2048 + w * 512];
  bf16* kd0_b1 = &ldsK[1][w * 512]; bf16* kd1_b1 = &ldsK[1][2048 + w * 512];
  bf16* vd0_b0 = &ldsV[0][w * 512]; bf16* vd1_b0 = &ldsV[0][2048 + w * 512];
  bf16* vd0_b1 = &ldsV[1][w * 512]; bf16* vd1_b1 = &ldsV[1][2048 + w * 512];

  auto stageTo = [&](bf16* kd0, bf16* kd1, bf16* vd0, bf16* vd1) {
    async_load16((const bf16*)kS0, kd0);
    async_load16((const bf16*)kS1, kd1);
    async_load16((const bf16*)vS0, vd0);
    async_load16((const bf16*)vS1, vd1);
    kS0 += kAdv; kS1 += kAdv; vS0 += vAdv; vS1 += vAdv;
  };

  const int kswz = (l15 & 7) << 4;
  const int xA = (lg * 16) ^ kswz;
  const int xB = (64 + lg * 16) ^ kswz;
  const char* krA0 = (const char*)&ldsK[0][0] + l15 * 128 + xA;
  const char* krB0 = (const char*)&ldsK[0][0] + l15 * 128 + xB;
  const char* krA1 = (const char*)&ldsK[1][0] + l15 * 128 + xA;
  const char* krB1 = (const char*)&ldsK[1][0] + l15 * 128 + xB;
  const char* vrA0 = (const char*)&ldsV[0][0] + l15 * 128 + xA;
  const char* vrB0 = (const char*)&ldsV[0][0] + l15 * 128 + xB;
  const char* vrA1 = (const char*)&ldsV[1][0] + l15 * 128 + xA;
  const char* vrB1 = (const char*)&ldsV[1][0] + l15 * 128 + xB;

  char* Pw = (char*)&ldsP[w][0];
  char* pwr[4];
#pragma unroll
  for (int j = 0; j < 4; ++j) {
    const int chunk = (j * 2 + (lg >> 1)) ^ (l15 & 7);
    pwr[j] = Pw + l15 * 128 + chunk * 16 + (lg & 1) * 8;
  }
  const char* paA = Pw + l15 * 128 + xA;
  const char* paB = Pw + l15 * 128 + xB;

  const bf16* Qbase = Qn + (size_t)(b * Ss + q0 + l15) * DMODEL + h * 64;
  bf16x8 bq0 = *(const bf16x8*)&Qbase[lg * 8];
  bf16x8 bq1 = *(const bf16x8*)&Qbase[32 + lg * 8];

  float m = 0.0f, l = 0.0f;
  f32x4 accO[4] = {};

  auto body = [&](const char* krA, const char* krB, const char* vrA, const char* vrB) {
    f32x4 sa[4] = {};
    __builtin_amdgcn_s_setprio(1);
#pragma unroll
    for (int j = 0; j < 4; ++j) {
      bf16x8 ak0 = *(const bf16x8*)(krA + j * 2048);
      bf16x8 ak1 = *(const bf16x8*)(krB + j * 2048);
      sa[j] = __builtin_amdgcn_mfma_f32_16x16x32_bf16(ak0, bq0, sa[j], 0, 0, 0);
      sa[j] = __builtin_amdgcn_mfma_f32_16x16x32_bf16(ak1, bq1, sa[j], 0, 0, 0);
    }
    __builtin_amdgcn_s_setprio(0);
    float pmaxr = -3.0e38f;
#pragma unroll
    for (int j = 0; j < 4; ++j)
#pragma unroll
      for (int r = 0; r < 4; ++r) pmaxr = fmaxf(pmaxr, sa[j][r]);
    if (__any(fmaf(pmaxr, SC2, -m) > THR)) {
      float px = fmaxf(pmaxr, __shfl_xor(pmaxr, 16, 64));
      px = fmaxf(px, __shfl_xor(px, 32, 64));
      float mnew = fmaxf(m, px * SC2);
      float corr = __builtin_amdgcn_exp2f(m - mnew);
      m = mnew; l *= corr;
      float cr[4];
#pragma unroll
      for (int r = 0; r < 4; ++r) cr[r] = __shfl(corr, lg * 4 + r, 64);
#pragma unroll
      for (int dj = 0; dj < 4; ++dj)
#pragma unroll
        for (int r = 0; r < 4; ++r) accO[dj][r] *= cr[r];
    }
    float p[4][4];
    float ts0 = 0.f, ts1 = 0.f;
#pragma unroll
    for (int j = 0; j < 4; ++j) {
#pragma unroll
      for (int r = 0; r < 4; ++r)
        p[j][r] = __builtin_amdgcn_exp2f(fmaf(sa[j][r], SC2, -m));
      ts0 += p[j][0] + p[j][2];
      ts1 += p[j][1] + p[j][3];
    }
    float ts = ts0 + ts1;
    ts += __shfl_xor(ts, 16, 64);
    ts += __shfl_xor(ts, 32, 64);
    l += ts;
#pragma unroll
    for (int j = 0; j < 4; ++j) {
      uint2 pw;
      pw.x = packbf(p[j][0], p[j][1]);
      pw.y = packbf(p[j][2], p[j][3]);
      *(uint2*)pwr[j] = pw;
    }
    bf16x8 pa0 = *(const bf16x8*)paA;
    bf16x8 pa1 = *(const bf16x8*)paB;
    __builtin_amdgcn_s_setprio(1);
#pragma unroll
    for (int dj = 0; dj < 4; ++dj) {
      bf16x8 bv0 = *(const bf16x8*)(vrA + dj * 2048);
      bf16x8 bv1 = *(const bf16x8*)(vrB + dj * 2048);
      accO[dj] = __builtin_amdgcn_mfma_f32_16x16x32_bf16(pa0, bv0, accO[dj], 0, 0, 0);
      accO[dj] = __builtin_amdgcn_mfma_f32_16x16x32_bf16(pa1, bv1, accO[dj], 0, 0, 0);
    }
    __builtin_amdgcn_s_setprio(0);
  };

  stageTo(kd0_b0, kd1_b0, vd0_b0, vd1_b0);
  for (int tt = 0; tt < 16; ++tt) {
    __syncthreads();
    stageTo(kd0_b1, kd1_b1, vd0_b1, vd1_b1);
    body(krA0, krB0, vrA0, vrB0);
    __syncthreads();
    if (tt < 15) stageTo(kd0_b0, kd1_b0, vd0_b0, vd1_b0);
    body(krA1, krB1, vrA1, vrB1);
  }

  float linv[4];
#pragma unroll
  for (int r = 0; r < 4; ++r) linv[r] = 1.0f / __shfl(l, lg * 4 + r, 64);
#pragma unroll
  for (int dj = 0; dj < 4; ++dj)
#pragma unroll
    for (int r = 0; r < 4; ++r)
      AO[(size_t)(b * Ss + q0 + lg * 4 + r) * DMODEL + h * 64 + dj * 16 + l15] =
          f2bf(accO[dj][r] * linv[r]);
}

// ---------------------------------------------------------------- launch
extern "C" void kernel_launch(void* const* d_in, const int* in_sizes, int n_in,
                              void* d_out, int out_size, void* d_ws, size_t ws_size,
                              hipStream_t stream) {
  const float* x      = (const float*)d_in[0];
  const float* Wdq    = (const float*)d_in[1];  const float* Wdq_b  = (const float*)d_in[2];
  const float* Wuq    = (const float*)d_in[3];  const float* Wuq_b  = (const float*)d_in[4];
  const float* Wqr    = (const float*)d_in[5];  const float* Wqr_b  = (const float*)d_in[6];
  const float* Wkr    = (const float*)d_in[7];  const float* Wkr_b  = (const float*)d_in[8];
  const float* Wdkv   = (const float*)d_in[9];  const float* Wdkv_b = (const float*)d_in[10];
  const float* Wuk    = (const float*)d_in[11]; const float* Wuk_b  = (const float*)d_in[12];
  const float* Wuv    = (const float*)d_in[13]; const float* Wuv_b  = (const float*)d_in[14];
  const float* Wo     = (const float*)d_in[15]; const float* Wo_b   = (const float*)d_in[16];

  // ---- workspace (~42 MB), round-9 layout ----
  char* ws = (char*)d_ws;
  size_t off = 0;
  bf16* WdqT   = (bf16*)(ws + off); off += (size_t)512  * 1024 * 2;
  bf16* WdkvT  = (bf16*)(ws + off); off += (size_t)512  * 1024 * 2;
  bf16* WuqT   = (bf16*)(ws + off); off += (size_t)1024 * 512  * 2;
  bf16* WqrT   = (bf16*)(ws + off); off += (size_t)1024 * 512  * 2;
  bf16* WukT   = (bf16*)(ws + off); off += (size_t)1024 * 512  * 2;
  bf16* WuvT   = (bf16*)(ws + off); off += (size_t)1024 * 512  * 2;
  bf16* WkrT   = (bf16*)(ws + off); off += (size_t)1024 * 1024 * 2;
  bf16* WoT    = (bf16*)(ws + off); off += (size_t)1024 * 1024 * 2;
  bf16* x_bf   = (bf16*)(ws + off); off += (size_t)NTOK * 1024 * 2;   // reused as Gupk
  bf16* ct     = (bf16*)(ws + off); off += (size_t)NTOK * 1024 * 2;   // [ct_q | ct_kv]
  bf16* Ga     = (bf16*)(ws + off); off += (size_t)NTOK * 1024 * 2;   // upQc, later AO
  bf16* VTr    = (bf16*)(ws + off); off += (size_t)NTOK * 1024 * 2;
  bf16* Gupk   = x_bf;                                 // x_bf dead after batch A
  bf16* Qn     = (bf16*)d_out;                         // dead before final GEMM
  bf16* Kn     = (bf16*)d_out + (size_t)NTOK * DMODEL;
  bf16* AO     = Ga;
  (void)ws_size; (void)in_sizes; (void)n_in; (void)out_size;

  // ---- merged transpose (1280 tiles) + x convert (4096 blocks) ----
  TransPack tp = {{
    { Wdq,  WdqT,  1024, 512,  0    },
    { Wdkv, WdkvT, 1024, 512,  128  },
    { Wuq,  WuqT,  512,  1024, 256  },
    { Wqr,  WqrT,  512,  1024, 384  },
    { Wuk,  WukT,  512,  1024, 512  },
    { Wuv,  WuvT,  512,  1024, 640  },
    { Wkr,  WkrT,  1024, 1024, 768  },
    { Wo,   WoT,   1024, 1024, 1024 },
  }};
  trans_conv_kernel<<<1280 + 4096, 256, 0, stream>>>(tp, x, x_bf, 1280);

  // ---- batch A (512 blocks): down = x@[Wdq|Wdkv] -> ct ; Kr = x@Wkr -> Kn region ----
  GemmBatch ba = {{
    { x_bf, WdqT, Wdq_b, Wdkv_b, ct, 1024, 1024, 1024, 1024, 512,     8, 0,       0 },
    { x_bf, WkrT, Wkr_b, Wkr_b,  Kn, 1024, 1024, 1024, 1024, INT_MAX, 8, 256,     0 },
    { 0, 0, 0, 0, 0, 0, 0, 0, 0, 0, 1, INT_MAX, 0 },
    { 0, 0, 0, 0, 0, 0, 0, 0, 0, 0, 1, INT_MAX, 0 },
  }};
  gemm_batch_kernel<<<512, 256, 0, stream>>>(ba);

  // ---- batch B (1024 blocks): upQc->Ga ; upQr->Qn ; upK->Gupk ; V^T->VTr ----
  GemmBatch bb = {{
    { ct,       WuqT,     Wuq_b, Wuq_b, Ga,   1024, 512,  1024, 512, INT_MAX, 8,  0,   0 },
    { ct,       WqrT,     Wqr_b, Wqr_b, Qn,   1024, 512,  1024, 512, INT_MAX, 8,  256, 0 },
    { ct + 512, WukT,     Wuk_b, Wuk_b, Gupk, 1024, 512,  1024, 512, INT_MAX, 8,  512, 0 },
    { WuvT,     ct + 512, Wuv_b, Wuv_b, VTr,  512,  1024, NTOK, 512, INT_MAX, 32, 768, 1 },
  }};
  gemm_batch_kernel<<<1024, 256, 0, stream>>>(bb);

  // combines (in place on the rope operand)
  combine_rope_kernel<<<NTOK * 128 / 256, 256, 0, stream>>>(Ga, 1024, Qn, 1024, Qn);
  combine_rope_kernel<<<NTOK * 128 / 256, 256, 0, stream>>>(Gupk, 1024, Kn, 1024, Kn);

  // attention (bh on x for XCD-L2 pinning)
  attn_kernel<<<dim3(32, 32), 256, 0, stream>>>(Qn, Kn, VTr, AO);

  // output projection (fp32 out), 128x64 tiles -> 512 blocks
  gemm_kernel_f32<<<dim3(16, 32), 256, 0, stream>>>(
      AO, 1024, WoT, 1024, Wo_b, (float*)d_out, 1024, 1024);
}

// Round 12
// 177.762 us; speedup vs baseline: 1.6745x; 1.0665x over previous
//
#include <hip/hip_runtime.h>
#include <hip/hip_bf16.h>
#include <math.h>
#include <limits.h>

typedef __hip_bfloat16 bf16;
typedef __bf16 bf16x8 __attribute__((ext_vector_type(8)));
typedef float  f32x4  __attribute__((ext_vector_type(4)));

#define DEVI __device__ __forceinline__

static constexpr int Bb     = 2;
static constexpr int Ss     = 2048;
static constexpr int DMODEL = 1024;
static constexpr int NTOK   = Bb * Ss;   // 4096

DEVI float bf2f(bf16 v) { return __bfloat162float(v); }
DEVI bf16  f2bf(float v) { return __float2bfloat16(v); }

DEVI unsigned int packbf(float lo, float hi) {
  union { bf16 b; unsigned short u; } a, c;
  a.b = f2bf(lo); c.b = f2bf(hi);
  return ((unsigned int)c.u << 16) | a.u;
}
DEVI float bfu2f(unsigned short u) {
  unsigned int x = (unsigned int)u << 16;
  float f; __builtin_memcpy(&f, &x, 4); return f;
}

DEVI void async_load16(const bf16* g, bf16* l) {
  __builtin_amdgcn_global_load_lds((const __attribute__((address_space(1))) void*)g,
                                   (__attribute__((address_space(3))) void*)l, 16, 0, 0);
}

// ---------------------------------------------------------------- transpose (1280 tiles) + convert (4096 blocks)
struct TransDesc { const float* src; bf16* dst; int R; int C; int tstart; };
struct TransPack { TransDesc d[8]; };

__global__ __launch_bounds__(256) void trans_conv_kernel(
    TransPack p, const float* __restrict__ cx, bf16* __restrict__ cxo, int tstartConv) {
  __shared__ bf16 tl[64][65];
  const int t = blockIdx.x;
  if (t >= tstartConv) {
    const int idx = (t - tstartConv) * 256 + threadIdx.x;
    const float4 v = ((const float4*)cx)[idx];
    uint2 o; o.x = packbf(v.x, v.y); o.y = packbf(v.z, v.w);
    *(uint2*)&cxo[(size_t)idx * 4] = o;
    return;
  }
  int i = 0;
#pragma unroll
  for (int j = 1; j < 8; ++j) if (t >= p.d[j].tstart) i = j;
  const float* __restrict__ in = p.d[i].src;
  bf16* __restrict__ out = p.d[i].dst;
  const int R = p.d[i].R, C = p.d[i].C;
  const int rel = t - p.d[i].tstart;
  const int tilesC = C >> 6;
  const int r0 = (rel / tilesC) * 64, c0 = (rel % tilesC) * 64;
  const int tc = threadIdx.x & 63, tr = threadIdx.x >> 6;
#pragma unroll
  for (int q = 0; q < 16; ++q) {
    int r = tr + q * 4;
    tl[r][tc] = f2bf(in[(size_t)(r0 + r) * C + c0 + tc]);
  }
  __syncthreads();
#pragma unroll
  for (int q = 0; q < 16; ++q) {
    int r = tr + q * 4;
    out[(size_t)(c0 + r) * R + r0 + tc] = tl[tc][r];
  }
}

// ---------------------------------------------------------------- batched GEMM (+optional in-place rope-add)
struct GemmDesc {
  const bf16* A; const bf16* WT; const float* b1; const float* b2; const bf16* ropeAdd; bf16* C;
  int lda, ldb, ldc, K, bsplit, nTX, blkStart, biasRow;
};
struct GemmBatch { GemmDesc d[4]; };

__global__ __launch_bounds__(256) void gemm_batch_kernel(GemmBatch gb) {
  const int t = blockIdx.x;
  int di = 0;
#pragma unroll
  for (int j = 1; j < 4; ++j) if (t >= gb.d[j].blkStart) di = j;
  const GemmDesc D = gb.d[di];
  const int rel = t - D.blkStart;
  const int tileN = (rel % D.nTX) * 128;
  const int tileM = (rel / D.nTX) * 128;

  __shared__ bf16 ldsA[128 * 32];
  __shared__ bf16 ldsB[128 * 32];
  const int tid = threadIdx.x;
  const int lane = tid & 63;
  const int w = tid >> 6;
  const int wr = w >> 1, wc = w & 1;
  const int l15 = lane & 15, lg = lane >> 4;
  const int lrow = lane >> 2;
  const int lcol = (lane & 3) * 8;

  f32x4 acc[4][4] = {};

  for (int k0 = 0; k0 < D.K; k0 += 32) {
    async_load16(D.A  + (size_t)(tileM + w * 32 +      lrow) * D.lda + k0 + lcol, &ldsA[(w * 32) * 32]);
    async_load16(D.A  + (size_t)(tileM + w * 32 + 16 + lrow) * D.lda + k0 + lcol, &ldsA[(w * 32 + 16) * 32]);
    async_load16(D.WT + (size_t)(tileN + w * 32 +      lrow) * D.ldb + k0 + lcol, &ldsB[(w * 32) * 32]);
    async_load16(D.WT + (size_t)(tileN + w * 32 + 16 + lrow) * D.ldb + k0 + lcol, &ldsB[(w * 32 + 16) * 32]);
    __syncthreads();

    bf16x8 af[4], bfr[4];
#pragma unroll
    for (int i = 0; i < 4; ++i) {
      af[i]  = *(const bf16x8*)&ldsA[(wr * 64 + i * 16 + l15) * 32 + lg * 8];
      bfr[i] = *(const bf16x8*)&ldsB[(wc * 64 + i * 16 + l15) * 32 + lg * 8];
    }
#pragma unroll
    for (int i = 0; i < 4; ++i)
#pragma unroll
      for (int j = 0; j < 4; ++j)
        acc[i][j] = __builtin_amdgcn_mfma_f32_16x16x32_bf16(af[i], bfr[j], acc[i][j], 0, 0, 0);
    __syncthreads();
  }

  const int mbase = tileM + wr * 64;
  const int nbase = tileN + wc * 64;
#pragma unroll
  for (int j = 0; j < 4; ++j) {
    int col = nbase + j * 16 + l15;
    float bvc = D.biasRow ? 0.0f : (col < D.bsplit ? D.b1[col] : D.b2[col - D.bsplit]);
    if (D.ropeAdd) {
      // out = acc + bias + rope(ropeAdd)[row][col]; in-place-safe (thread loads its full pair)
      const int pcol = col >> 1;
      const bool odd = (col & 1) != 0;
      const float th = exp2f(-26.5754247f * (float)pcol) * (1.0f / 512.0f);
#pragma unroll
      for (int i = 0; i < 4; ++i)
#pragma unroll
        for (int r = 0; r < 4; ++r) {
          int row = mbase + i * 16 + lg * 4 + r;
          int s = row & (Ss - 1);
          unsigned int pr = *(const unsigned int*)((const char*)D.ropeAdd +
                              (size_t)row * D.ldc * 2 + (size_t)(col & ~1) * 2);
          float ke = bfu2f((unsigned short)(pr & 0xffff));
          float ko = bfu2f((unsigned short)(pr >> 16));
          float c = 1.0f, sn = (float)s * th;
          if (pcol == 0) { float rr = (float)s * (1.0f / 512.0f); c = cosf(rr); sn = sinf(rr); }
          float add = odd ? (ko * c + ke * sn) : (ke * c - ko * sn);
          D.C[(size_t)row * D.ldc + col] = f2bf(acc[i][j][r] + bvc + add);
        }
    } else {
#pragma unroll
      for (int i = 0; i < 4; ++i)
#pragma unroll
        for (int r = 0; r < 4; ++r) {
          int row = mbase + i * 16 + lg * 4 + r;
          float bv = D.biasRow ? D.b1[row] : bvc;
          D.C[(size_t)row * D.ldc + col] = f2bf(acc[i][j][r] + bv);
        }
    }
  }
}

// ---------------------------------------------------------------- GEMM fp32-out (outproj), 128x64 tiles
__global__ __launch_bounds__(256) void gemm_kernel_f32(
    const bf16* __restrict__ A, int lda,
    const bf16* __restrict__ WT, int ldb,
    const float* __restrict__ b1,
    float* __restrict__ Cout, int ldc, int K) {
  __shared__ bf16 ldsA[128 * 32];
  __shared__ bf16 ldsB[64 * 32];
  const int tid = threadIdx.x;
  const int lane = tid & 63;
  const int w = tid >> 6;
  const int tileM = blockIdx.y * 128;
  const int tileN = blockIdx.x * 64;
  const int l15 = lane & 15, lg = lane >> 4;
  const int lrow = lane >> 2;
  const int lcol = (lane & 3) * 8;

  f32x4 acc[2][4] = {};

  for (int k0 = 0; k0 < K; k0 += 32) {
    async_load16(A  + (size_t)(tileM + w * 32 +      lrow) * lda + k0 + lcol, &ldsA[(w * 32) * 32]);
    async_load16(A  + (size_t)(tileM + w * 32 + 16 + lrow) * lda + k0 + lcol, &ldsA[(w * 32 + 16) * 32]);
    async_load16(WT + (size_t)(tileN + w * 16 + lrow) * ldb + k0 + lcol, &ldsB[(w * 16) * 32]);
    __syncthreads();

    bf16x8 af[2], bfr[4];
#pragma unroll
    for (int i = 0; i < 2; ++i)
      af[i]  = *(const bf16x8*)&ldsA[(w * 32 + i * 16 + l15) * 32 + lg * 8];
#pragma unroll
    for (int j = 0; j < 4; ++j)
      bfr[j] = *(const bf16x8*)&ldsB[(j * 16 + l15) * 32 + lg * 8];
#pragma unroll
    for (int i = 0; i < 2; ++i)
#pragma unroll
      for (int j = 0; j < 4; ++j)
        acc[i][j] = __builtin_amdgcn_mfma_f32_16x16x32_bf16(af[i], bfr[j], acc[i][j], 0, 0, 0);
    __syncthreads();
  }

#pragma unroll
  for (int j = 0; j < 4; ++j) {
    int col = tileN + j * 16 + l15;
    float bvc = b1[col];
#pragma unroll
    for (int i = 0; i < 2; ++i)
#pragma unroll
      for (int r = 0; r < 4; ++r) {
        int row = tileM + w * 32 + i * 16 + lg * 4 + r;
        Cout[(size_t)row * ldc + col] = acc[i][j][r] + bvc;
      }
  }
}

// ---------------------------------------------------------------- attention v6
// grid (32 bh, 16 qt); 4 waves x 32 q-rows (2 sub-tiles) -> K/V LDS reads amortize 2x.
// Q = Qc + rope(Qr) fused at Q-load. K/V dbuf XOR-swizzled, raw exp2, defer-max, setprio.
__global__ __launch_bounds__(256) void attn_kernel(
    const bf16* __restrict__ Qcm, const bf16* __restrict__ Qrm,
    const bf16* __restrict__ Kn, const bf16* __restrict__ VT,
    bf16* __restrict__ AO) {
  const int bh = blockIdx.x, qt = blockIdx.y;   // bh%8 == XCD -> K/V stays in one L2
  const int b = bh >> 4, h = bh & 15;
  const int tid = threadIdx.x, lane = tid & 63, w = tid >> 6;
  const int q0 = qt * 128 + w * 32;
  const int l15 = lane & 15, lg = lane >> 4;
  const float SC2 = 0.044736075f;    // (1/sqrt(1040)) * log2(e)
  const float THR = 11.5415603f;     // 8 * log2(e)

  __shared__ bf16 ldsK[2][64 * 64];
  __shared__ bf16 ldsV[2][64 * 64];
  __shared__ bf16 ldsP[4][32 * 64];

  const bf16* Kg = Kn + (size_t)(b * Ss) * DMODEL + h * 64;
  const bf16* Vg = VT + (size_t)(h * 64) * NTOK + b * Ss;

  const int r0 = tid >> 3;
  const int srcb = ((tid & 7) * 16) ^ ((r0 & 7) << 4);
  const char* kS0 = (const char*)(Kg + (size_t)r0 * DMODEL) + srcb;
  const char* kS1 = (const char*)(Kg + (size_t)(32 + r0) * DMODEL) + srcb;
  const char* vS0 = (const char*)(Vg + (size_t)r0 * NTOK) + srcb;
  const char* vS1 = (const char*)(Vg + (size_t)(32 + r0) * NTOK) + srcb;
  const ptrdiff_t kAdv = (ptrdiff_t)64 * DMODEL * 2;
  const ptrdiff_t vAdv = 128;

  bf16* kd0_b0 = &ldsK[0][w * 512]; bf16* kd1_b0 = &ldsK[0][2048 + w * 512];
  bf16* kd0_b1 = &ldsK[1][w * 512]; bf16* kd1_b1 = &ldsK[1][2048 + w * 512];
  bf16* vd0_b0 = &ldsV[0][w * 512]; bf16* vd1_b0 = &ldsV[0][2048 + w * 512];
  bf16* vd0_b1 = &ldsV[1][w * 512]; bf16* vd1_b1 = &ldsV[1][2048 + w * 512];

  auto stageTo = [&](bf16* kd0, bf16* kd1, bf16* vd0, bf16* vd1) {
    async_load16((const bf16*)kS0, kd0);
    async_load16((const bf16*)kS1, kd1);
    async_load16((const bf16*)vS0, vd0);
    async_load16((const bf16*)vS1, vd1);
    kS0 += kAdv; kS1 += kAdv; vS0 += vAdv; vS1 += vAdv;
  };

  stageTo(kd0_b0, kd1_b0, vd0_b0, vd1_b0);   // tile 0 in flight while Q is built

  const int kswz = (l15 & 7) << 4;
  const int xA = (lg * 16) ^ kswz;
  const int xB = (64 + lg * 16) ^ kswz;
  const char* krA0 = (const char*)&ldsK[0][0] + l15 * 128 + xA;
  const char* krB0 = (const char*)&ldsK[0][0] + l15 * 128 + xB;
  const char* krA1 = (const char*)&ldsK[1][0] + l15 * 128 + xA;
  const char* krB1 = (const char*)&ldsK[1][0] + l15 * 128 + xB;
  const char* vrA0 = (const char*)&ldsV[0][0] + l15 * 128 + xA;
  const char* vrB0 = (const char*)&ldsV[0][0] + l15 * 128 + xB;
  const char* vrA1 = (const char*)&ldsV[1][0] + l15 * 128 + xA;
  const char* vrB1 = (const char*)&ldsV[1][0] + l15 * 128 + xB;

  char* Pw = (char*)&ldsP[w][0];
  char* pwr[4];
#pragma unroll
  for (int j = 0; j < 4; ++j) {
    const int chunk = (j * 2 + (lg >> 1)) ^ (l15 & 7);
    pwr[j] = Pw + l15 * 128 + chunk * 16 + (lg & 1) * 8;
  }
  const char* paA = Pw + l15 * 128 + xA;
  const char* paB = Pw + l15 * 128 + xB;

  // ---- Q-combine at load: bq[i][kg] = Qc + rope(Qr), rows q0 + i*16 + l15
  const int p0 = h * 32 + lg * 4;          // + kg*16 + pp
  float th[2][4];
#pragma unroll
  for (int kg = 0; kg < 2; ++kg)
#pragma unroll
    for (int pp = 0; pp < 4; ++pp)
      th[kg][pp] = exp2f(-26.5754247f * (float)(p0 + kg * 16 + pp)) * (1.0f / 512.0f);

  bf16x8 bq[2][2];
#pragma unroll
  for (int i = 0; i < 2; ++i) {
    const int s = q0 + i * 16 + l15;
    const size_t rowoff = (size_t)(b * Ss + s) * DMODEL + h * 64;
#pragma unroll
    for (int kg = 0; kg < 2; ++kg) {
      union { bf16x8 v; unsigned short u[8]; } gc, gr;
      union { bf16x8 v; unsigned int w2[4]; } qo;
      gc.v = *(const bf16x8*)&Qcm[rowoff + kg * 32 + lg * 8];
      gr.v = *(const bf16x8*)&Qrm[rowoff + kg * 32 + lg * 8];
#pragma unroll
      for (int pp = 0; pp < 4; ++pp) {
        float c = 1.0f, sn = (float)s * th[kg][pp];
        if (p0 + kg * 16 + pp == 0) { float rr = (float)s * (1.0f / 512.0f); c = cosf(rr); sn = sinf(rr); }
        float g0 = bfu2f(gr.u[2 * pp]), g1 = bfu2f(gr.u[2 * pp + 1]);
        qo.w2[pp] = packbf(bfu2f(gc.u[2 * pp])     + g0 * c - g1 * sn,
                           bfu2f(gc.u[2 * pp + 1]) + g1 * c + g0 * sn);
      }
      bq[i][kg] = qo.v;
    }
  }

  float m[2] = { 0.0f, 0.0f }, l[2] = { 0.0f, 0.0f };
  f32x4 accO[2][4] = {};

  auto body = [&](const char* krA, const char* krB, const char* vrA, const char* vrB) {
    f32x4 sa[4][2] = {};
    __builtin_amdgcn_s_setprio(1);
#pragma unroll
    for (int j = 0; j < 4; ++j) {
      bf16x8 ak0 = *(const bf16x8*)(krA + j * 2048);
      bf16x8 ak1 = *(const bf16x8*)(krB + j * 2048);
#pragma unroll
      for (int i = 0; i < 2; ++i) {
        sa[j][i] = __builtin_amdgcn_mfma_f32_16x16x32_bf16(ak0, bq[i][0], sa[j][i], 0, 0, 0);
        sa[j][i] = __builtin_amdgcn_mfma_f32_16x16x32_bf16(ak1, bq[i][1], sa[j][i], 0, 0, 0);
      }
    }
    __builtin_amdgcn_s_setprio(0);
#pragma unroll
    for (int i = 0; i < 2; ++i) {
      float pmaxr = -3.0e38f;
#pragma unroll
      for (int j = 0; j < 4; ++j)
#pragma unroll
        for (int r = 0; r < 4; ++r) pmaxr = fmaxf(pmaxr, sa[j][i][r]);
      if (__any(fmaf(pmaxr, SC2, -m[i]) > THR)) {
        float px = fmaxf(pmaxr, __shfl_xor(pmaxr, 16, 64));
        px = fmaxf(px, __shfl_xor(px, 32, 64));
        float mnew = fmaxf(m[i], px * SC2);
        float corr = __builtin_amdgcn_exp2f(m[i] - mnew);
        m[i] = mnew; l[i] *= corr;
        float cr[4];
#pragma unroll
        for (int r = 0; r < 4; ++r) cr[r] = __shfl(corr, lg * 4 + r, 64);
#pragma unroll
        for (int dj = 0; dj < 4; ++dj)
#pragma unroll
          for (int r = 0; r < 4; ++r) accO[i][dj][r] *= cr[r];
      }
      float p[4][4];
      float ts0 = 0.f, ts1 = 0.f;
#pragma unroll
      for (int j = 0; j < 4; ++j) {
#pragma unroll
        for (int r = 0; r < 4; ++r)
          p[j][r] = __builtin_amdgcn_exp2f(fmaf(sa[j][i][r], SC2, -m[i]));
        ts0 += p[j][0] + p[j][2];
        ts1 += p[j][1] + p[j][3];
      }
      float ts = ts0 + ts1;
      ts += __shfl_xor(ts, 16, 64);
      ts += __shfl_xor(ts, 32, 64);
      l[i] += ts;
#pragma unroll
      for (int j = 0; j < 4; ++j) {
        uint2 pw;
        pw.x = packbf(p[j][0], p[j][1]);
        pw.y = packbf(p[j][2], p[j][3]);
        *(uint2*)(pwr[j] + i * 2048) = pw;
      }
    }
    bf16x8 pa[2][2];
#pragma unroll
    for (int i = 0; i < 2; ++i) {
      pa[i][0] = *(const bf16x8*)(paA + i * 2048);
      pa[i][1] = *(const bf16x8*)(paB + i * 2048);
    }
    __builtin_amdgcn_s_setprio(1);
#pragma unroll
    for (int dj = 0; dj < 4; ++dj) {
      bf16x8 bv0 = *(const bf16x8*)(vrA + dj * 2048);
      bf16x8 bv1 = *(const bf16x8*)(vrB + dj * 2048);
#pragma unroll
      for (int i = 0; i < 2; ++i) {
        accO[i][dj] = __builtin_amdgcn_mfma_f32_16x16x32_bf16(pa[i][0], bv0, accO[i][dj], 0, 0, 0);
        accO[i][dj] = __builtin_amdgcn_mfma_f32_16x16x32_bf16(pa[i][1], bv1, accO[i][dj], 0, 0, 0);
      }
    }
    __builtin_amdgcn_s_setprio(0);
  };

  for (int tt = 0; tt < 16; ++tt) {
    __syncthreads();                                 // buf0 ready; buf1 free
    stageTo(kd0_b1, kd1_b1, vd0_b1, vd1_b1);
    body(krA0, krB0, vrA0, vrB0);
    __syncthreads();                                 // buf1 ready; buf0 free
    if (tt < 15) stageTo(kd0_b0, kd1_b0, vd0_b0, vd1_b0);
    body(krA1, krB1, vrA1, vrB1);
  }

#pragma unroll
  for (int i = 0; i < 2; ++i) {
    float linv[4];
#pragma unroll
    for (int r = 0; r < 4; ++r) linv[r] = 1.0f / __shfl(l[i], lg * 4 + r, 64);
#pragma unroll
    for (int dj = 0; dj < 4; ++dj)
#pragma unroll
      for (int r = 0; r < 4; ++r)
        AO[(size_t)(b * Ss + q0 + i * 16 + lg * 4 + r) * DMODEL + h * 64 + dj * 16 + l15] =
            f2bf(accO[i][dj][r] * linv[r]);
  }
}

// ---------------------------------------------------------------- launch
extern "C" void kernel_launch(void* const* d_in, const int* in_sizes, int n_in,
                              void* d_out, int out_size, void* d_ws, size_t ws_size,
                              hipStream_t stream) {
  const float* x      = (const float*)d_in[0];
  const float* Wdq    = (const float*)d_in[1];  const float* Wdq_b  = (const float*)d_in[2];
  const float* Wuq    = (const float*)d_in[3];  const float* Wuq_b  = (const float*)d_in[4];
  const float* Wqr    = (const float*)d_in[5];  const float* Wqr_b  = (const float*)d_in[6];
  const float* Wkr    = (const float*)d_in[7];  const float* Wkr_b  = (const float*)d_in[8];
  const float* Wdkv   = (const float*)d_in[9];  const float* Wdkv_b = (const float*)d_in[10];
  const float* Wuk    = (const float*)d_in[11]; const float* Wuk_b  = (const float*)d_in[12];
  const float* Wuv    = (const float*)d_in[13]; const float* Wuv_b  = (const float*)d_in[14];
  const float* Wo     = (const float*)d_in[15]; const float* Wo_b   = (const float*)d_in[16];

  // ---- workspace ----
  char* ws = (char*)d_ws;
  size_t off = 0;
  bf16* WdqT   = (bf16*)(ws + off); off += (size_t)512  * 1024 * 2;
  bf16* WdkvT  = (bf16*)(ws + off); off += (size_t)512  * 1024 * 2;
  bf16* WuqT   = (bf16*)(ws + off); off += (size_t)1024 * 512  * 2;
  bf16* WqrT   = (bf16*)(ws + off); off += (size_t)1024 * 512  * 2;
  bf16* WukT   = (bf16*)(ws + off); off += (size_t)1024 * 512  * 2;
  bf16* WuvT   = (bf16*)(ws + off); off += (size_t)1024 * 512  * 2;
  bf16* WkrT   = (bf16*)(ws + off); off += (size_t)1024 * 1024 * 2;
  bf16* WoT    = (bf16*)(ws + off); off += (size_t)1024 * 1024 * 2;
  bf16* x_bf   = (bf16*)(ws + off); off += (size_t)NTOK * 1024 * 2;
  bf16* ct     = (bf16*)(ws + off); off += (size_t)NTOK * 1024 * 2;   // [ct_q | ct_kv]
  bf16* Ga     = (bf16*)(ws + off); off += (size_t)NTOK * 1024 * 2;   // Qc, later AO
  bf16* VTr    = (bf16*)(ws + off); off += (size_t)NTOK * 1024 * 2;
  bf16* Qn     = (bf16*)d_out;                         // raw Qr; dead before final GEMM
  bf16* Kn     = (bf16*)d_out + (size_t)NTOK * DMODEL; // Kr, then final K (in-place rope-add)
  bf16* AO     = Ga;
  (void)ws_size; (void)in_sizes; (void)n_in; (void)out_size;

  // ---- merged transpose + x convert ----
  TransPack tp = {{
    { Wdq,  WdqT,  1024, 512,  0    },
    { Wdkv, WdkvT, 1024, 512,  128  },
    { Wuq,  WuqT,  512,  1024, 256  },
    { Wqr,  WqrT,  512,  1024, 384  },
    { Wuk,  WukT,  512,  1024, 512  },
    { Wuv,  WuvT,  512,  1024, 640  },
    { Wkr,  WkrT,  1024, 1024, 768  },
    { Wo,   WoT,   1024, 1024, 1024 },
  }};
  trans_conv_kernel<<<1280 + 4096, 256, 0, stream>>>(tp, x, x_bf, 1280);

  // ---- batch A (512): down = x@[Wdq|Wdkv] -> ct ; Kr = x@Wkr + kr_b -> Kn ----
  GemmBatch ba = {{
    { x_bf, WdqT, Wdq_b, Wdkv_b, 0, ct, 1024, 1024, 1024, 1024, 512,     8, 0,       0 },
    { x_bf, WkrT, Wkr_b, Wkr_b,  0, Kn, 1024, 1024, 1024, 1024, INT_MAX, 8, 256,     0 },
    { 0, 0, 0, 0, 0, 0, 0, 0, 0, 0, 0, 1, INT_MAX, 0 },
    { 0, 0, 0, 0, 0, 0, 0, 0, 0, 0, 0, 1, INT_MAX, 0 },
  }};
  gemm_batch_kernel<<<512, 256, 0, stream>>>(ba);

  // ---- batch B (1024): Qc->Ga ; Qr->Qn ; K = upK + rope(Kr) in place ; V^T->VTr ----
  GemmBatch bb = {{
    { ct,       WuqT,     Wuq_b, Wuq_b, 0,  Ga,  1024, 512,  1024, 512, INT_MAX, 8,  0,   0 },
    { ct,       WqrT,     Wqr_b, Wqr_b, 0,  Qn,  1024, 512,  1024, 512, INT_MAX, 8,  256, 0 },
    { ct + 512, WukT,     Wuk_b, Wuk_b, Kn, Kn,  1024, 512,  1024, 512, INT_MAX, 8,  512, 0 },
    { WuvT,     ct + 512, Wuv_b, Wuv_b, 0,  VTr, 512,  1024, NTOK, 512, INT_MAX, 32, 768, 1 },
  }};
  gemm_batch_kernel<<<1024, 256, 0, stream>>>(bb);

  // ---- attention (Q-combine fused at Q-load) ----
  attn_kernel<<<dim3(32, 16), 256, 0, stream>>>(Ga, Qn, Kn, VTr, AO);

  // ---- output projection ----
  gemm_kernel_f32<<<dim3(16, 32), 256, 0, stream>>>(
      AO, 1024, WoT, 1024, Wo_b, (float*)d_out, 1024, 1024);
}

// Round 13
// 168.045 us; speedup vs baseline: 1.7713x; 1.0578x over previous
//
#include <hip/hip_runtime.h>
#include <hip/hip_bf16.h>
#include <math.h>
#include <limits.h>

typedef __hip_bfloat16 bf16;
typedef __bf16 bf16x8 __attribute__((ext_vector_type(8)));
typedef float  f32x4  __attribute__((ext_vector_type(4)));

#define DEVI __device__ __forceinline__

static constexpr int Bb     = 2;
static constexpr int Ss     = 2048;
static constexpr int DMODEL = 1024;
static constexpr int NTOK   = Bb * Ss;   // 4096

DEVI float bf2f(bf16 v) { return __bfloat162float(v); }
DEVI bf16  f2bf(float v) { return __float2bfloat16(v); }

DEVI unsigned int packbf(float lo, float hi) {
  union { bf16 b; unsigned short u; } a, c;
  a.b = f2bf(lo); c.b = f2bf(hi);
  return ((unsigned int)c.u << 16) | a.u;
}
DEVI float bfu2f(unsigned short u) {
  unsigned int x = (unsigned int)u << 16;
  float f; __builtin_memcpy(&f, &x, 4); return f;
}

DEVI void async_load16(const bf16* g, bf16* l) {
  __builtin_amdgcn_global_load_lds((const __attribute__((address_space(1))) void*)g,
                                   (__attribute__((address_space(3))) void*)l, 16, 0, 0);
}

// ---------------------------------------------------------------- transpose(+add) + convert + bias-sum
struct TransDesc { const float* src; const float* src2; bf16* dst; int R; int C; int tstart; };
struct TransPack { TransDesc d[8]; };

__global__ __launch_bounds__(256) void trans_conv_kernel(
    TransPack p, const float* __restrict__ cx, bf16* __restrict__ cxo, int tstartConv,
    const float* __restrict__ ba1, const float* __restrict__ ba2,
    float* __restrict__ bsum, int tstartB) {
  __shared__ bf16 tl[64][65];
  const int t = blockIdx.x;
  if (t >= tstartB) {
    // ---- bias-sum range: qsum_b = Wuq_b + Wqr_b (4 blocks x 256)
    const int j = (t - tstartB) * 256 + threadIdx.x;
    bsum[j] = ba1[j] + ba2[j];
    return;
  }
  if (t >= tstartConv) {
    // ---- convert range: one float4 per thread
    const int idx = (t - tstartConv) * 256 + threadIdx.x;
    const float4 v = ((const float4*)cx)[idx];
    uint2 o; o.x = packbf(v.x, v.y); o.y = packbf(v.z, v.w);
    *(uint2*)&cxo[(size_t)idx * 4] = o;
    return;
  }
  // ---- transpose range (optional elementwise add of src2)
  int i = 0;
#pragma unroll
  for (int j = 1; j < 8; ++j) if (t >= p.d[j].tstart) i = j;
  const float* __restrict__ in  = p.d[i].src;
  const float* __restrict__ in2 = p.d[i].src2;
  bf16* __restrict__ out = p.d[i].dst;
  const int R = p.d[i].R, C = p.d[i].C;
  const int rel = t - p.d[i].tstart;
  const int tilesC = C >> 6;
  const int r0 = (rel / tilesC) * 64, c0 = (rel % tilesC) * 64;
  const int tc = threadIdx.x & 63, tr = threadIdx.x >> 6;
#pragma unroll
  for (int q = 0; q < 16; ++q) {
    int r = tr + q * 4;
    float v = in[(size_t)(r0 + r) * C + c0 + tc];
    if (in2) v += in2[(size_t)(r0 + r) * C + c0 + tc];
    tl[r][tc] = f2bf(v);
  }
  __syncthreads();
#pragma unroll
  for (int q = 0; q < 16; ++q) {
    int r = tr + q * 4;
    out[(size_t)(c0 + r) * R + r0 + tc] = tl[tc][r];
  }
}

// ---------------------------------------------------------------- batched GEMM (+optional in-place Kr-add)
// addm path: out = acc + bias + addm[row][col] (identity-rope for p>=1; real trig on pair 0)
struct GemmDesc {
  const bf16* A; const bf16* WT; const float* b1; const float* b2; const bf16* addm; bf16* C;
  int lda, ldb, ldc, K, bsplit, nTX, blkStart, biasRow;
};
struct GemmBatch { GemmDesc d[4]; };

__global__ __launch_bounds__(256) void gemm_batch_kernel(GemmBatch gb) {
  const int t = blockIdx.x;
  int di = 0;
#pragma unroll
  for (int j = 1; j < 4; ++j) if (t >= gb.d[j].blkStart) di = j;
  const GemmDesc D = gb.d[di];
  const int rel = t - D.blkStart;
  const int tileN = (rel % D.nTX) * 128;
  const int tileM = (rel / D.nTX) * 128;

  __shared__ bf16 ldsA[128 * 32];
  __shared__ bf16 ldsB[128 * 32];
  const int tid = threadIdx.x;
  const int lane = tid & 63;
  const int w = tid >> 6;
  const int wr = w >> 1, wc = w & 1;
  const int l15 = lane & 15, lg = lane >> 4;
  const int lrow = lane >> 2;
  const int lcol = (lane & 3) * 8;

  f32x4 acc[4][4] = {};

  for (int k0 = 0; k0 < D.K; k0 += 32) {
    async_load16(D.A  + (size_t)(tileM + w * 32 +      lrow) * D.lda + k0 + lcol, &ldsA[(w * 32) * 32]);
    async_load16(D.A  + (size_t)(tileM + w * 32 + 16 + lrow) * D.lda + k0 + lcol, &ldsA[(w * 32 + 16) * 32]);
    async_load16(D.WT + (size_t)(tileN + w * 32 +      lrow) * D.ldb + k0 + lcol, &ldsB[(w * 32) * 32]);
    async_load16(D.WT + (size_t)(tileN + w * 32 + 16 + lrow) * D.ldb + k0 + lcol, &ldsB[(w * 32 + 16) * 32]);
    __syncthreads();

    bf16x8 af[4], bfr[4];
#pragma unroll
    for (int i = 0; i < 4; ++i) {
      af[i]  = *(const bf16x8*)&ldsA[(wr * 64 + i * 16 + l15) * 32 + lg * 8];
      bfr[i] = *(const bf16x8*)&ldsB[(wc * 64 + i * 16 + l15) * 32 + lg * 8];
    }
#pragma unroll
    for (int i = 0; i < 4; ++i)
#pragma unroll
      for (int j = 0; j < 4; ++j)
        acc[i][j] = __builtin_amdgcn_mfma_f32_16x16x32_bf16(af[i], bfr[j], acc[i][j], 0, 0, 0);
    __syncthreads();
  }

  const int mbase = tileM + wr * 64;
  const int nbase = tileN + wc * 64;
#pragma unroll
  for (int j = 0; j < 4; ++j) {
    int col = nbase + j * 16 + l15;
    float bvc = D.biasRow ? 0.0f : (col < D.bsplit ? D.b1[col] : D.b2[col - D.bsplit]);
    if (D.addm) {
      const int pcol = col >> 1;
      const bool odd = (col & 1) != 0;
#pragma unroll
      for (int i = 0; i < 4; ++i)
#pragma unroll
        for (int r = 0; r < 4; ++r) {
          int row = mbase + i * 16 + lg * 4 + r;
          unsigned int pr = *(const unsigned int*)((const char*)D.addm +
                              (size_t)row * D.ldc * 2 + (size_t)(col & ~1) * 2);
          float ke = bfu2f((unsigned short)(pr & 0xffff));
          float ko = bfu2f((unsigned short)(pr >> 16));
          float add;
          if (pcol == 0) {
            float rr = (float)(row & (Ss - 1)) * (1.0f / 512.0f);
            float c = cosf(rr), sn = sinf(rr);
            add = odd ? (ko * c + ke * sn) : (ke * c - ko * sn);
          } else {
            add = odd ? ko : ke;           // rope == identity for p>=1 at bf16
          }
          D.C[(size_t)row * D.ldc + col] = f2bf(acc[i][j][r] + bvc + add);
        }
    } else {
#pragma unroll
      for (int i = 0; i < 4; ++i)
#pragma unroll
        for (int r = 0; r < 4; ++r) {
          int row = mbase + i * 16 + lg * 4 + r;
          float bv = D.biasRow ? D.b1[row] : bvc;
          D.C[(size_t)row * D.ldc + col] = f2bf(acc[i][j][r] + bv);
        }
    }
  }
}

// ---------------------------------------------------------------- GEMM fp32-out (outproj), 128x64 tiles
__global__ __launch_bounds__(256) void gemm_kernel_f32(
    const bf16* __restrict__ A, int lda,
    const bf16* __restrict__ WT, int ldb,
    const float* __restrict__ b1,
    float* __restrict__ Cout, int ldc, int K) {
  __shared__ bf16 ldsA[128 * 32];
  __shared__ bf16 ldsB[64 * 32];
  const int tid = threadIdx.x;
  const int lane = tid & 63;
  const int w = tid >> 6;
  const int tileM = blockIdx.y * 128;
  const int tileN = blockIdx.x * 64;
  const int l15 = lane & 15, lg = lane >> 4;
  const int lrow = lane >> 2;
  const int lcol = (lane & 3) * 8;

  f32x4 acc[2][4] = {};

  for (int k0 = 0; k0 < K; k0 += 32) {
    async_load16(A  + (size_t)(tileM + w * 32 +      lrow) * lda + k0 + lcol, &ldsA[(w * 32) * 32]);
    async_load16(A  + (size_t)(tileM + w * 32 + 16 + lrow) * lda + k0 + lcol, &ldsA[(w * 32 + 16) * 32]);
    async_load16(WT + (size_t)(tileN + w * 16 + lrow) * ldb + k0 + lcol, &ldsB[(w * 16) * 32]);
    __syncthreads();

    bf16x8 af[2], bfr[4];
#pragma unroll
    for (int i = 0; i < 2; ++i)
      af[i]  = *(const bf16x8*)&ldsA[(w * 32 + i * 16 + l15) * 32 + lg * 8];
#pragma unroll
    for (int j = 0; j < 4; ++j)
      bfr[j] = *(const bf16x8*)&ldsB[(j * 16 + l15) * 32 + lg * 8];
#pragma unroll
    for (int i = 0; i < 2; ++i)
#pragma unroll
      for (int j = 0; j < 4; ++j)
        acc[i][j] = __builtin_amdgcn_mfma_f32_16x16x32_bf16(af[i], bfr[j], acc[i][j], 0, 0, 0);
    __syncthreads();
  }

#pragma unroll
  for (int j = 0; j < 4; ++j) {
    int col = tileN + j * 16 + l15;
    float bvc = b1[col];
#pragma unroll
    for (int i = 0; i < 2; ++i)
#pragma unroll
      for (int r = 0; r < 4; ++r) {
        int row = tileM + w * 32 + i * 16 + lg * 4 + r;
        Cout[(size_t)row * ldc + col] = acc[i][j][r] + bvc;
      }
  }
}

// ---------------------------------------------------------------- Q p=0 fixup
// wave per row: Qr01 = ct_q[row] . Wqr[:,0:2] + Wqr_b[0:2]; rotate into Qsum dims 0,1
__global__ __launch_bounds__(256) void fixup_q_kernel(
    const bf16* __restrict__ ct, const float* __restrict__ Wqr,
    const float* __restrict__ Wqr_b, bf16* __restrict__ Q) {
  const int row = blockIdx.x * 4 + (threadIdx.x >> 6);
  const int lane = threadIdx.x & 63;
  const bf16* cr = ct + (size_t)row * 1024 + lane * 8;      // ct_q = cols [0,512)
  const float* wq = Wqr + (size_t)(lane * 8) * 1024;
  float q0 = 0.f, q1 = 0.f;
#pragma unroll
  for (int e = 0; e < 8; ++e) {
    float xv = bf2f(cr[e]);
    q0 = fmaf(xv, wq[e * 1024 + 0], q0);
    q1 = fmaf(xv, wq[e * 1024 + 1], q1);
  }
#pragma unroll
  for (int d = 32; d >= 1; d >>= 1) {
    q0 += __shfl_xor(q0, d, 64);
    q1 += __shfl_xor(q1, d, 64);
  }
  if (lane == 0) {
    const float Qr0 = q0 + Wqr_b[0], Qr1 = q1 + Wqr_b[1];
    const float rr = (float)(row & (Ss - 1)) * (1.0f / 512.0f);
    const float cm1 = cosf(rr) - 1.0f, sn = sinf(rr);
    const size_t base = (size_t)row * DMODEL;
    Q[base]     = f2bf(bf2f(Q[base])     + Qr0 * cm1 - Qr1 * sn);
    Q[base + 1] = f2bf(bf2f(Q[base + 1]) + Qr1 * cm1 + Qr0 * sn);
  }
}

// ---------------------------------------------------------------- attention v7
// grid (32 bh, 16 qt); 4 waves x 32 q-rows. Plain Q loads (Qsum precombined).
// Shuffle-free softmax main path (per-lane partial l, reduced once in epilogue).
__global__ __launch_bounds__(256) void attn_kernel(
    const bf16* __restrict__ Qm, const bf16* __restrict__ Kn,
    const bf16* __restrict__ VT, bf16* __restrict__ AO) {
  const int bh = blockIdx.x, qt = blockIdx.y;   // bh%8 == XCD -> K/V stays in one L2
  const int b = bh >> 4, h = bh & 15;
  const int tid = threadIdx.x, lane = tid & 63, w = tid >> 6;
  const int q0 = qt * 128 + w * 32;
  const int l15 = lane & 15, lg = lane >> 4;
  const float SC2 = 0.044736075f;    // (1/sqrt(1040)) * log2(e)
  const float THR = 11.5415603f;     // 8 * log2(e)

  __shared__ bf16 ldsK[2][64 * 64];
  __shared__ bf16 ldsV[2][64 * 64];
  __shared__ bf16 ldsP[4][32 * 64];

  const bf16* Kg = Kn + (size_t)(b * Ss) * DMODEL + h * 64;
  const bf16* Vg = VT + (size_t)(h * 64) * NTOK + b * Ss;

  const int r0 = tid >> 3;
  const int srcb = ((tid & 7) * 16) ^ ((r0 & 7) << 4);
  const char* kS0 = (const char*)(Kg + (size_t)r0 * DMODEL) + srcb;
  const char* kS1 = (const char*)(Kg + (size_t)(32 + r0) * DMODEL) + srcb;
  const char* vS0 = (const char*)(Vg + (size_t)r0 * NTOK) + srcb;
  const char* vS1 = (const char*)(Vg + (size_t)(32 + r0) * NTOK) + srcb;
  const ptrdiff_t kAdv = (ptrdiff_t)64 * DMODEL * 2;
  const ptrdiff_t vAdv = 128;

  bf16* kd0_b0 = &ldsK[0][w * 512]; bf16* kd1_b0 = &ldsK[0][2048 + w * 512];
  bf16* kd0_b1 = &ldsK[1][w * 512]; bf16* kd1_b1 = &ldsK[1][2048 + w * 512];
  bf16* vd0_b0 = &ldsV[0][w * 512]; bf16* vd1_b0 = &ldsV[0][2048 + w * 512];
  bf16* vd0_b1 = &ldsV[1][w * 512]; bf16* vd1_b1 = &ldsV[1][2048 + w * 512];

  auto stageTo = [&](bf16* kd0, bf16* kd1, bf16* vd0, bf16* vd1) {
    async_load16((const bf16*)kS0, kd0);
    async_load16((const bf16*)kS1, kd1);
    async_load16((const bf16*)vS0, vd0);
    async_load16((const bf16*)vS1, vd1);
    kS0 += kAdv; kS1 += kAdv; vS0 += vAdv; vS1 += vAdv;
  };

  stageTo(kd0_b0, kd1_b0, vd0_b0, vd1_b0);   // tile 0 in flight while Q loads

  const int kswz = (l15 & 7) << 4;
  const int xA = (lg * 16) ^ kswz;
  const int xB = (64 + lg * 16) ^ kswz;
  const char* krA0 = (const char*)&ldsK[0][0] + l15 * 128 + xA;
  const char* krB0 = (const char*)&ldsK[0][0] + l15 * 128 + xB;
  const char* krA1 = (const char*)&ldsK[1][0] + l15 * 128 + xA;
  const char* krB1 = (const char*)&ldsK[1][0] + l15 * 128 + xB;
  const char* vrA0 = (const char*)&ldsV[0][0] + l15 * 128 + xA;
  const char* vrB0 = (const char*)&ldsV[0][0] + l15 * 128 + xB;
  const char* vrA1 = (const char*)&ldsV[1][0] + l15 * 128 + xA;
  const char* vrB1 = (const char*)&ldsV[1][0] + l15 * 128 + xB;

  char* Pw = (char*)&ldsP[w][0];
  char* pwr[4];
#pragma unroll
  for (int j = 0; j < 4; ++j) {
    const int chunk = (j * 2 + (lg >> 1)) ^ (l15 & 7);
    pwr[j] = Pw + l15 * 128 + chunk * 16 + (lg & 1) * 8;
  }
  const char* paA = Pw + l15 * 128 + xA;
  const char* paB = Pw + l15 * 128 + xB;

  // ---- plain Q loads (Qsum precombined): rows q0 + i*16 + l15
  bf16x8 bq[2][2];
#pragma unroll
  for (int i = 0; i < 2; ++i) {
    const size_t rowoff = (size_t)(b * Ss + q0 + i * 16 + l15) * DMODEL + h * 64;
    bq[i][0] = *(const bf16x8*)&Qm[rowoff + lg * 8];
    bq[i][1] = *(const bf16x8*)&Qm[rowoff + 32 + lg * 8];
  }

  float m[2] = { 0.0f, 0.0f }, l[2] = { 0.0f, 0.0f };   // l = per-lane partial
  f32x4 accO[2][4] = {};

  auto body = [&](const char* krA, const char* krB, const char* vrA, const char* vrB) {
    f32x4 sa[4][2] = {};
    __builtin_amdgcn_s_setprio(1);
#pragma unroll
    for (int j = 0; j < 4; ++j) {
      bf16x8 ak0 = *(const bf16x8*)(krA + j * 2048);
      bf16x8 ak1 = *(const bf16x8*)(krB + j * 2048);
#pragma unroll
      for (int i = 0; i < 2; ++i) {
        sa[j][i] = __builtin_amdgcn_mfma_f32_16x16x32_bf16(ak0, bq[i][0], sa[j][i], 0, 0, 0);
        sa[j][i] = __builtin_amdgcn_mfma_f32_16x16x32_bf16(ak1, bq[i][1], sa[j][i], 0, 0, 0);
      }
    }
    __builtin_amdgcn_s_setprio(0);
#pragma unroll
    for (int i = 0; i < 2; ++i) {
      float pmaxr = -3.0e38f;
#pragma unroll
      for (int j = 0; j < 4; ++j)
#pragma unroll
        for (int r = 0; r < 4; ++r) pmaxr = fmaxf(pmaxr, sa[j][i][r]);
      if (__any(fmaf(pmaxr, SC2, -m[i]) > THR)) {        // cold on sane logits
        float px = fmaxf(pmaxr, __shfl_xor(pmaxr, 16, 64));
        px = fmaxf(px, __shfl_xor(px, 32, 64));
        float mnew = fmaxf(m[i], px * SC2);
        float corr = __builtin_amdgcn_exp2f(m[i] - mnew);
        m[i] = mnew; l[i] *= corr;                        // partial-l scales uniformly
        float cr[4];
#pragma unroll
        for (int r = 0; r < 4; ++r) cr[r] = __shfl(corr, lg * 4 + r, 64);
#pragma unroll
        for (int dj = 0; dj < 4; ++dj)
#pragma unroll
          for (int r = 0; r < 4; ++r) accO[i][dj][r] *= cr[r];
      }
      float p[4][4];
      float ts = 0.f;
#pragma unroll
      for (int j = 0; j < 4; ++j)
#pragma unroll
        for (int r = 0; r < 4; ++r) {
          p[j][r] = __builtin_amdgcn_exp2f(fmaf(sa[j][i][r], SC2, -m[i]));
          ts += p[j][r];
        }
      l[i] += ts;                                        // NO cross-lane reduce here
#pragma unroll
      for (int j = 0; j < 4; ++j) {
        uint2 pw;
        pw.x = packbf(p[j][0], p[j][1]);
        pw.y = packbf(p[j][2], p[j][3]);
        *(uint2*)(pwr[j] + i * 2048) = pw;
      }
    }
    bf16x8 pa[2][2];
#pragma unroll
    for (int i = 0; i < 2; ++i) {
      pa[i][0] = *(const bf16x8*)(paA + i * 2048);
      pa[i][1] = *(const bf16x8*)(paB + i * 2048);
    }
    __builtin_amdgcn_s_setprio(1);
#pragma unroll
    for (int dj = 0; dj < 4; ++dj) {
      bf16x8 bv0 = *(const bf16x8*)(vrA + dj * 2048);
      bf16x8 bv1 = *(const bf16x8*)(vrB + dj * 2048);
#pragma unroll
      for (int i = 0; i < 2; ++i) {
        accO[i][dj] = __builtin_amdgcn_mfma_f32_16x16x32_bf16(pa[i][0], bv0, accO[i][dj], 0, 0, 0);
        accO[i][dj] = __builtin_amdgcn_mfma_f32_16x16x32_bf16(pa[i][1], bv1, accO[i][dj], 0, 0, 0);
      }
    }
    __builtin_amdgcn_s_setprio(0);
  };

  for (int tt = 0; tt < 16; ++tt) {
    __syncthreads();                                 // buf0 ready; buf1 free
    stageTo(kd0_b1, kd1_b1, vd0_b1, vd1_b1);
    body(krA0, krB0, vrA0, vrB0);
    __syncthreads();                                 // buf1 ready; buf0 free
    if (tt < 15) stageTo(kd0_b0, kd1_b0, vd0_b0, vd1_b0);
    body(krA1, krB1, vrA1, vrB1);
  }

  // ---- epilogue: reduce partial l across the 4 lanes sharing l15, then normalize
#pragma unroll
  for (int i = 0; i < 2; ++i) {
    float lt = l[i];
    lt += __shfl_xor(lt, 16, 64);
    lt += __shfl_xor(lt, 32, 64);
    float linv[4];
#pragma unroll
    for (int r = 0; r < 4; ++r) linv[r] = 1.0f / __shfl(lt, lg * 4 + r, 64);
#pragma unroll
    for (int dj = 0; dj < 4; ++dj)
#pragma unroll
      for (int r = 0; r < 4; ++r)
        AO[(size_t)(b * Ss + q0 + i * 16 + lg * 4 + r) * DMODEL + h * 64 + dj * 16 + l15] =
            f2bf(accO[i][dj][r] * linv[r]);
  }
}

// ---------------------------------------------------------------- launch
extern "C" void kernel_launch(void* const* d_in, const int* in_sizes, int n_in,
                              void* d_out, int out_size, void* d_ws, size_t ws_size,
                              hipStream_t stream) {
  const float* x      = (const float*)d_in[0];
  const float* Wdq    = (const float*)d_in[1];  const float* Wdq_b  = (const float*)d_in[2];
  const float* Wuq    = (const float*)d_in[3];  const float* Wuq_b  = (const float*)d_in[4];
  const float* Wqr    = (const float*)d_in[5];  const float* Wqr_b  = (const float*)d_in[6];
  const float* Wkr    = (const float*)d_in[7];  const float* Wkr_b  = (const float*)d_in[8];
  const float* Wdkv   = (const float*)d_in[9];  const float* Wdkv_b = (const float*)d_in[10];
  const float* Wuk    = (const float*)d_in[11]; const float* Wuk_b  = (const float*)d_in[12];
  const float* Wuv    = (const float*)d_in[13]; const float* Wuv_b  = (const float*)d_in[14];
  const float* Wo     = (const float*)d_in[15]; const float* Wo_b   = (const float*)d_in[16];

  // ---- workspace ----
  char* ws = (char*)d_ws;
  size_t off = 0;
  bf16* WdqT   = (bf16*)(ws + off); off += (size_t)512  * 1024 * 2;
  bf16* WdkvT  = (bf16*)(ws + off); off += (size_t)512  * 1024 * 2;
  bf16* WuqqrT = (bf16*)(ws + off); off += (size_t)1024 * 512  * 2;   // (Wuq+Wqr)^T
  bf16* WukT   = (bf16*)(ws + off); off += (size_t)1024 * 512  * 2;
  bf16* WuvT   = (bf16*)(ws + off); off += (size_t)1024 * 512  * 2;
  bf16* WkrT   = (bf16*)(ws + off); off += (size_t)1024 * 1024 * 2;
  bf16* WoT    = (bf16*)(ws + off); off += (size_t)1024 * 1024 * 2;
  bf16* x_bf   = (bf16*)(ws + off); off += (size_t)NTOK * 1024 * 2;
  bf16* ct     = (bf16*)(ws + off); off += (size_t)NTOK * 1024 * 2;   // [ct_q | ct_kv]
  bf16* Ga     = (bf16*)(ws + off); off += (size_t)NTOK * 1024 * 2;   // Qsum, later AO
  bf16* VTr    = (bf16*)(ws + off); off += (size_t)NTOK * 1024 * 2;
  float* qsum_b= (float*)(ws + off); off += 1024 * 4;
  bf16* Kn     = (bf16*)d_out + (size_t)NTOK * DMODEL; // Kr, then final K (in-place add)
  bf16* AO     = Ga;
  (void)ws_size; (void)in_sizes; (void)n_in; (void)out_size;

  // ---- merged transpose(+add) + x convert + qsum_b ----
  TransPack tp = {{
    { Wdq,  0,   WdqT,   1024, 512,  0    },
    { Wdkv, 0,   WdkvT,  1024, 512,  128  },
    { Wuq,  Wqr, WuqqrT, 512,  1024, 256  },
    { Wuk,  0,   WukT,   512,  1024, 384  },
    { Wuv,  0,   WuvT,   512,  1024, 512  },
    { Wkr,  0,   WkrT,   1024, 1024, 640  },
    { Wo,   0,   WoT,    1024, 1024, 896  },
    { 0, 0, 0, 0, 0, 1 << 30 },
  }};
  trans_conv_kernel<<<1152 + 4096 + 4, 256, 0, stream>>>(
      tp, x, x_bf, 1152, Wuq_b, Wqr_b, qsum_b, 1152 + 4096);

  // ---- batch A (512): down = x@[Wdq|Wdkv] -> ct ; Kr = x@Wkr + kr_b -> Kn ----
  GemmBatch ba = {{
    { x_bf, WdqT, Wdq_b, Wdkv_b, 0, ct, 1024, 1024, 1024, 1024, 512,     8, 0,       0 },
    { x_bf, WkrT, Wkr_b, Wkr_b,  0, Kn, 1024, 1024, 1024, 1024, INT_MAX, 8, 256,     0 },
    { 0, 0, 0, 0, 0, 0, 0, 0, 0, 0, 0, 1, INT_MAX, 0 },
    { 0, 0, 0, 0, 0, 0, 0, 0, 0, 0, 0, 1, INT_MAX, 0 },
  }};
  gemm_batch_kernel<<<512, 256, 0, stream>>>(ba);

  // ---- batch B (768): Qsum -> Ga ; K = upK + Kr(identity-rope, trig on pair 0) in place ; V^T ----
  GemmBatch bb = {{
    { ct,       WuqqrT,   qsum_b, qsum_b, 0,  Ga,  1024, 512,  1024, 512, INT_MAX, 8,  0,   0 },
    { ct + 512, WukT,     Wuk_b,  Wuk_b,  Kn, Kn,  1024, 512,  1024, 512, INT_MAX, 8,  256, 0 },
    { WuvT,     ct + 512, Wuv_b,  Wuv_b,  0,  VTr, 512,  1024, NTOK, 512, INT_MAX, 32, 512, 1 },
    { 0, 0, 0, 0, 0, 0, 0, 0, 0, 0, 0, 1, 1 << 30, 0 },
  }};
  gemm_batch_kernel<<<768, 256, 0, stream>>>(bb);

  // ---- Q p=0 fixup (dims 0,1 of Qsum) ----
  fixup_q_kernel<<<NTOK / 4, 256, 0, stream>>>(ct, Wqr, Wqr_b, Ga);

  // ---- attention ----
  attn_kernel<<<dim3(32, 16), 256, 0, stream>>>(Ga, Kn, VTr, AO);

  // ---- output projection ----
  gemm_kernel_f32<<<dim3(16, 32), 256, 0, stream>>>(
      AO, 1024, WoT, 1024, Wo_b, (float*)d_out, 1024, 1024);
}